// Round 2
// baseline (1092.456 us; speedup 1.0000x reference)
//
#include <hip/hip_runtime.h>
#include <hip/hip_bf16.h>

typedef unsigned short ushort_t;
typedef short short8 __attribute__((ext_vector_type(8)));
typedef float floatx4 __attribute__((ext_vector_type(4)));

#define SA 168   // Xin row stride in bf16 elems: 336B = 21*16 (16B-aligned, odd-16 -> ~conflict-free)
#define SW 104   // K=96 weight / Hhat stride: 208B = 13*16
#define NQ 110592
#define CVOL 32768

__device__ __forceinline__ float bf2f(ushort_t u) { return __uint_as_float(((unsigned)u) << 16); }
__device__ __forceinline__ ushort_t f2bf(float f) {
    unsigned u = __float_as_uint(f);
    unsigned r = (u + 0x7fffu + ((u >> 16) & 1u)) >> 16;
    return (ushort_t)r;
}
__device__ __forceinline__ unsigned encodeMin(float x) {
    unsigned u = __float_as_uint(x);
    return (u & 0x80000000u) ? ~u : (u | 0x80000000u);
}
__device__ __forceinline__ float decodeMin(unsigned key) {
    unsigned u = (key & 0x80000000u) ? (key ^ 0x80000000u) : ~key;
    return __uint_as_float(u);
}

__device__ __constant__ float FREQ[8] = {
    1.0f, 1.2228445f, 1.4953488f, 1.8285791f,
    2.2360680f, 2.7343640f, 3.3437015f, 4.0888269f
};

// ---------------- prep: transpose+pad fp32 weights into ws as bf16, init min keys ----------------
__global__ void decoder_prep(const float* __restrict__ w00, const float* __restrict__ w01,
                             const float* __restrict__ w02, const float* __restrict__ w10,
                             const float* __restrict__ w11, const float* __restrict__ w12,
                             const float* __restrict__ pw, ushort_t* __restrict__ wsW,
                             unsigned* __restrict__ keys) {
    int idx = blockIdx.x * 256 + threadIdx.x;
    if (idx < 3) keys[idx] = 0xFFFFFFFFu;
    if (idx >= 77184) return;
    float val = 0.f;
    if (idx < 16128)        { int n = idx / 168,            k = idx - n * 168;            if (k < 156) val = w00[k * 96 + n]; }
    else if (idx < 26112)   { int t = idx - 16128, n = t / 104, k = t - n * 104;          if (k < 96)  val = w01[k * 96 + n]; }
    else if (idx < 36096)   { int t = idx - 26112, n = t / 104, k = t - n * 104;          if (k < 96)  val = w02[k * 96 + n]; }
    else if (idx < 52224)   { int t = idx - 36096, n = t / 168, k = t - n * 168;          if (k < 156) val = w10[k * 96 + n]; }
    else if (idx < 62208)   { int t = idx - 52224, n = t / 104, k = t - n * 104;          if (k < 96)  val = w11[k * 96 + n]; }
    else if (idx < 72192)   { int t = idx - 62208, n = t / 104, k = t - n * 104;          if (k < 96)  val = w12[k * 96 + n]; }
    else                    { int t = idx - 72192, n = t / 104, k = t - n * 104;          if (k < 96 && n < 45) val = pw[k * 45 + n]; }
    wsW[idx] = f2bf(val);
}

// ---------------- prepass: global min of base_c = org + ci*vox - q over all points ----------------
__global__ void decoder_prepass(const float* __restrict__ qc, const float* __restrict__ ext,
                                unsigned* __restrict__ keys) {
    __shared__ unsigned mk[3];
    int tid = threadIdx.x;
    int lane = tid & 63;
    if (tid < 3) mk[tid] = 0xFFFFFFFFu;
    __syncthreads();
    int p = blockIdx.x * 256 + tid;
    #pragma unroll
    for (int c = 0; c < 3; ++c) {
        float org = ext[c * CVOL];
        float vox = fabsf(ext[c * CVOL + 1057] - org);
        float q = qc[c * NQ + p];
        float nf = rintf((q - org) / vox);
        int ci = (int)nf; ci = ci < 0 ? 0 : (ci > 30 ? 30 : ci);
        float base = org + (float)ci * vox - q;
        for (int off = 32; off > 0; off >>= 1) base = fminf(base, __shfl_xor(base, off));
        if (lane == 0) atomicMin(&mk[c], encodeMin(base));
    }
    __syncthreads();
    if (tid < 3) atomicMin(&keys[tid], mk[tid]);
}

// ---------------- main fused kernel ----------------
__global__ __launch_bounds__(256, 2) void decoder_main(
    const float* __restrict__ cv, const float* __restrict__ ext,
    const float* __restrict__ qvx, const float* __restrict__ qc,
    const float* __restrict__ b00, const float* __restrict__ b01, const float* __restrict__ b02,
    const float* __restrict__ b10, const float* __restrict__ b11, const float* __restrict__ b12,
    const float* __restrict__ pb, const ushort_t* __restrict__ wsW,
    const unsigned* __restrict__ minKeys, float* __restrict__ out)
{
    __shared__ ushort_t Xin[128 * SA];     // rows = (point, corner), cols = [h(96) | feats(60) | pad]
    __shared__ ushort_t Wstg[96 * SA];     // per-layer staged transposed weights
    __shared__ ushort_t Hhat[16 * SW];     // corner-blended h
    __shared__ float ptQ[3][16], ptBase[3][16], ptT[3][16];
    __shared__ int ptCI[3][16];
    __shared__ float wcorn[16][8];

    const int tid = threadIdx.x;
    const int lane = tid & 63;
    const int wv = tid >> 6;
    const int quad = lane >> 4;
    const int l16 = lane & 15;
    const int wm = wv & 1, wn = wv >> 1;   // 2x2 wave grid over (M-half, N-half)
    const int p0 = blockIdx.x * 16;

    // broadcast scalars
    float vox[3], org[3], lim[3], inv3v[3], qv[3], mrel[3][2];
    #pragma unroll
    for (int c = 0; c < 3; ++c) {
        org[c] = ext[c * CVOL];
        vox[c] = fabsf(ext[c * CVOL + 1057] - org[c]);
        lim[c] = -0.5f * vox[c] + 1e-7f;
        inv3v[c] = 1.0f / (1.5f * vox[c]);
        qv[c] = qvx[c];
        float mb = decodeMin(minKeys[c]);
        mrel[c][0] = fmaxf(mb, lim[c]);
        mrel[c][1] = fmaxf(mb + vox[c], lim[c]);
    }

    // per-point setup
    if (tid < 64) {
        int p = tid >> 2, c = tid & 3;
        if (c < 3) {
            float q = qc[c * NQ + p0 + p];
            float nf = rintf((q - org[c]) / vox[c]);   // RNE == jnp.round
            int ci = (int)nf; ci = ci < 0 ? 0 : (ci > 30 ? 30 : ci);
            float base = org[c] + (float)ci * vox[c] - q;
            float rel0 = fmaxf(base, lim[c]);
            float g = fminf(fmaxf((rel0 - 0.5f) * 2.0f, -1.0f + 1e-7f), 1.0f - 1e-7f);
            ptQ[c][p] = q; ptCI[c][p] = ci; ptBase[c][p] = base; ptT[c][p] = (g + 1.0f) * 0.5f;
        }
    }
    __syncthreads();

    // trilinear corner weights (NOTE reference's channel swap: i->t[2], j->t[1], k->t[0])
    if (tid < 128) {
        int p = tid >> 3, corner = tid & 7;
        int i = corner >> 2, j = (corner >> 1) & 1, k = corner & 1;
        float wx = i ? ptT[2][p] : 1.0f - ptT[2][p];
        float wy = j ? ptT[1][p] : 1.0f - ptT[1][p];
        float wz = k ? ptT[0][p] : 1.0f - ptT[0][p];
        wcorn[p][corner] = wx * wy * wz;
    }

    // coord features: threads 0..127 write cols 96..107 + zero pads; 128..255 write Fourier enc
    {
        int r = tid & 127;
        int p = r >> 3, corner = r & 7;
        const int i0 = corner >> 2, i1 = (corner >> 1) & 1, i2 = corner & 1;
        int io[3] = {i0, i1, i2};
        float rn[3];
        #pragma unroll
        for (int c = 0; c < 3; ++c) {
            float rel = fmaxf(ptBase[c][p] + (float)io[c] * vox[c], lim[c]);
            rn[c] = (rel - mrel[c][io[c]]) * inv3v[c];
        }
        ushort_t* row = &Xin[r * SA];
        if (tid < 128) {
            #pragma unroll
            for (int c = 0; c < 3; ++c) {
                row[96 + c]  = f2bf(qv[c]);
                row[99 + c]  = f2bf(org[c] + (float)(ptCI[c][p] + io[c]) * vox[c]);
                row[102 + c] = f2bf(ptQ[c][p]);
                row[105 + c] = f2bf(rn[c]);
            }
            #pragma unroll
            for (int z = 156; z < SA; ++z) row[z] = 0;
        } else {
            #pragma unroll
            for (int c = 0; c < 3; ++c) {
                #pragma unroll
                for (int m = 0; m < 8; ++m) {
                    float s, co;
                    sincospif(2.0f * rn[c] * FREQ[m], &s, &co);   // sin/cos(2*pi*rn*f)
                    row[108 + c * 16 + m] = f2bf(s);
                    row[108 + c * 16 + 8 + m] = f2bf(co);
                }
            }
        }
    }

    // gather context values (fp32 -> bf16): 16 points x 8 corners x 96 ch
    {
        int p = tid >> 4, sub = tid & 15;
        int zc = ptCI[2][p];
        #pragma unroll
        for (int ij = 0; ij < 4; ++ij) {
            int i = ij >> 1, j = ij & 1;
            int cell = (ptCI[0][p] + i) * 1024 + (ptCI[1][p] + j) * 32 + zc;
            int r0 = p * 8 + ij * 2;
            #pragma unroll
            for (int cc = 0; cc < 6; ++cc) {
                int ch = sub * 6 + cc;
                const float* g = &cv[ch * CVOL + cell];
                Xin[r0 * SA + ch] = f2bf(g[0]);
                Xin[(r0 + 1) * SA + ch] = f2bf(g[1]);
            }
        }
    }
    __syncthreads();

    // two skip blocks
    #pragma unroll 1
    for (int blk = 0; blk < 2; ++blk) {
        // snapshot h_old for the residual (same thread wrote these values -> no barrier needed)
        float hold[4][3][4];
        #pragma unroll
        for (int mt = 0; mt < 4; ++mt)
            #pragma unroll
            for (int nt = 0; nt < 3; ++nt)
                #pragma unroll
                for (int r = 0; r < 4; ++r)
                    hold[mt][nt][r] = bf2f(Xin[(64 * wm + 16 * mt + quad * 4 + r) * SA + 48 * wn + 16 * nt + l16]);

        #pragma unroll 1
        for (int l = 0; l < 3; ++l) {
            __syncthreads();
            {   // stage this layer's transposed weights
                int off = (blk ? 36096 : 0) + (l == 1 ? 16128 : (l == 2 ? 26112 : 0));
                int nd = l ? 4992 : 8064;
                const unsigned* s = (const unsigned*)(wsW + off);
                unsigned* d = (unsigned*)Wstg;
                for (int f = tid; f < nd; f += 256) d[f] = s[f];
            }
            __syncthreads();

            const int nkc = l ? 3 : 5;
            const int sw = l ? SW : SA;
            floatx4 acc[4][3];
            #pragma unroll
            for (int mt = 0; mt < 4; ++mt)
                #pragma unroll
                for (int nt = 0; nt < 3; ++nt) acc[mt][nt] = (floatx4){0.f, 0.f, 0.f, 0.f};

            for (int kc = 0; kc < nkc; ++kc) {
                short8 a[4];
                #pragma unroll
                for (int mt = 0; mt < 4; ++mt)
                    a[mt] = *(const short8*)&Xin[(64 * wm + 16 * mt + l16) * SA + kc * 32 + quad * 8];
                #pragma unroll
                for (int nt = 0; nt < 3; ++nt) {
                    short8 bfrag = *(const short8*)&Wstg[(48 * wn + 16 * nt + l16) * sw + kc * 32 + quad * 8];
                    #pragma unroll
                    for (int mt = 0; mt < 4; ++mt)
                        acc[mt][nt] = __builtin_amdgcn_mfma_f32_16x16x32_bf16(a[mt], bfrag, acc[mt][nt], 0, 0, 0);
                }
            }

            const float* bias = (l == 0) ? (blk ? b10 : b00) : (l == 1) ? (blk ? b11 : b01) : (blk ? b12 : b02);
            #pragma unroll
            for (int nt = 0; nt < 3; ++nt) {
                float bv = bias[48 * wn + 16 * nt + l16];
                #pragma unroll
                for (int mt = 0; mt < 4; ++mt)
                    #pragma unroll
                    for (int r = 0; r < 4; ++r) {
                        float z = acc[mt][nt][r] + bv;
                        float s = z / (1.0f + __expf(-z));       // silu
                        if (l == 2) s += hold[mt][nt][r];        // residual
                        acc[mt][nt][r] = s;
                    }
            }
            __syncthreads();   // everyone's A-reads done before overwriting h
            #pragma unroll
            for (int mt = 0; mt < 4; ++mt)
                #pragma unroll
                for (int nt = 0; nt < 3; ++nt)
                    #pragma unroll
                    for (int r = 0; r < 4; ++r)
                        Xin[(64 * wm + 16 * mt + quad * 4 + r) * SA + 48 * wn + 16 * nt + l16] = f2bf(acc[mt][nt][r]);
        }
    }
    __syncthreads();

    // blend 8 corners into hhat (post layer is linear, weights sum to 1 -> blend before GEMM)
    {
        int p = tid >> 4, s6 = (tid & 15) * 6;
        float w8[8];
        #pragma unroll
        for (int c = 0; c < 8; ++c) w8[c] = wcorn[p][c];
        #pragma unroll
        for (int cc = 0; cc < 6; ++cc) {
            int col = s6 + cc;
            float sum = 0.f;
            #pragma unroll
            for (int c = 0; c < 8; ++c) sum += w8[c] * bf2f(Xin[(p * 8 + c) * SA + col]);
            Hhat[p * SW + col] = f2bf(sum);
        }
    }
    __syncthreads();
    {   // stage post weights
        const unsigned* s = (const unsigned*)(wsW + 72192);
        unsigned* d = (unsigned*)Wstg;
        for (int f = tid; f < 2496; f += 256) d[f] = s[f];
    }
    __syncthreads();

    // post GEMM: 16 points x 48(45) out channels, waves 0..2 take one n-tile each
    if (wv < 3) {
        floatx4 acc = (floatx4){0.f, 0.f, 0.f, 0.f};
        #pragma unroll
        for (int kc = 0; kc < 3; ++kc) {
            short8 a = *(const short8*)&Hhat[l16 * SW + kc * 32 + quad * 8];
            short8 bfrag = *(const short8*)&Wstg[(16 * wv + l16) * SW + kc * 32 + quad * 8];
            acc = __builtin_amdgcn_mfma_f32_16x16x32_bf16(a, bfrag, acc, 0, 0, 0);
        }
        int n = 16 * wv + l16;
        if (n < 45) {
            float bv = pb[n];
            float4 v;
            v.x = acc[0] + bv; v.y = acc[1] + bv; v.z = acc[2] + bv; v.w = acc[3] + bv;
            *(float4*)&out[n * NQ + p0 + quad * 4] = v;
        }
    }
}

extern "C" void kernel_launch(void* const* d_in, const int* in_sizes, int n_in,
                              void* d_out, int out_size, void* d_ws, size_t ws_size,
                              hipStream_t stream) {
    (void)in_sizes; (void)n_in; (void)out_size; (void)ws_size;
    const float* cv  = (const float*)d_in[0];
    const float* ext = (const float*)d_in[1];
    const float* qvx = (const float*)d_in[2];
    const float* qc  = (const float*)d_in[3];
    const float* w00 = (const float*)d_in[4];
    const float* b00 = (const float*)d_in[5];
    const float* w01 = (const float*)d_in[6];
    const float* b01 = (const float*)d_in[7];
    const float* w02 = (const float*)d_in[8];
    const float* b02 = (const float*)d_in[9];
    const float* w10 = (const float*)d_in[10];
    const float* b10 = (const float*)d_in[11];
    const float* w11 = (const float*)d_in[12];
    const float* b11 = (const float*)d_in[13];
    const float* w12 = (const float*)d_in[14];
    const float* b12 = (const float*)d_in[15];
    const float* pw  = (const float*)d_in[16];
    const float* pb  = (const float*)d_in[17];

    unsigned* keys = (unsigned*)d_ws;                       // 3 uint min-keys
    ushort_t* wsW  = (ushort_t*)((char*)d_ws + 64);         // 77184 bf16 transposed weights

    decoder_prep<<<302, 256, 0, stream>>>(w00, w01, w02, w10, w11, w12, pw, wsW, keys);
    decoder_prepass<<<432, 256, 0, stream>>>(qc, ext, keys);
    decoder_main<<<6912, 256, 0, stream>>>(cv, ext, qvx, qc,
                                           b00, b01, b02, b10, b11, b12,
                                           pb, wsW, keys, (float*)d_out);
}

// Round 3
// 557.052 us; speedup vs baseline: 1.9611x; 1.9611x over previous
//
#include <hip/hip_runtime.h>
#include <hip/hip_bf16.h>

typedef unsigned short ushort_t;
typedef short short8 __attribute__((ext_vector_type(8)));
typedef float floatx4 __attribute__((ext_vector_type(4)));

#define SA 168   // Xin row stride in bf16 elems: 336B = 21*16 (16B-aligned)
#define SW 104   // K=96 weight / Hhat stride: 208B = 13*16
#define NQ 110592
#define CVOL 32768

__device__ __forceinline__ float bf2f(ushort_t u) { return __uint_as_float(((unsigned)u) << 16); }
__device__ __forceinline__ ushort_t f2bf(float f) {
    unsigned u = __float_as_uint(f);
    unsigned r = (u + 0x7fffu + ((u >> 16) & 1u)) >> 16;
    return (ushort_t)r;
}
__device__ __forceinline__ unsigned encodeMin(float x) {
    unsigned u = __float_as_uint(x);
    return (u & 0x80000000u) ? ~u : (u | 0x80000000u);
}
__device__ __forceinline__ float decodeMin(unsigned key) {
    unsigned u = (key & 0x80000000u) ? (key ^ 0x80000000u) : ~key;
    return __uint_as_float(u);
}

__device__ __constant__ float FREQ[8] = {
    1.0f, 1.2228445f, 1.4953488f, 1.8285791f,
    2.2360680f, 2.7343640f, 3.3437015f, 4.0888269f
};

// ---------------- transpose cv [96][32768] fp32 -> cvT [32768][96] bf16 ----------------
__global__ void decoder_txp(const float* __restrict__ cv, ushort_t* __restrict__ cvT) {
    __shared__ ushort_t ld[128 * SW];          // 26.6 KB, stride 104 elems (208B = 13*16)
    int tid = threadIdx.x;
    int base = blockIdx.x * 128;
    int cl = tid & 127, h = tid >> 7;
    #pragma unroll 4
    for (int ch = h * 48; ch < h * 48 + 48; ++ch)
        ld[cl * SW + ch] = f2bf(cv[ch * CVOL + base + cl]);   // coalesced read along cells
    __syncthreads();
    #pragma unroll
    for (int it = 0; it < 6; ++it) {
        int idx = it * 256 + tid;
        int r = idx / 12, c = idx - r * 12;
        *(uint4*)&cvT[(base + r) * 96 + c * 8] = *(const uint4*)&ld[r * SW + c * 8];  // coalesced 16B write
    }
}

// ---------------- prep: transpose+pad fp32 weights into ws as bf16, init min keys ----------------
__global__ void decoder_prep(const float* __restrict__ w00, const float* __restrict__ w01,
                             const float* __restrict__ w02, const float* __restrict__ w10,
                             const float* __restrict__ w11, const float* __restrict__ w12,
                             const float* __restrict__ pw, ushort_t* __restrict__ wsW,
                             unsigned* __restrict__ keys) {
    int idx = blockIdx.x * 256 + threadIdx.x;
    if (idx < 3) keys[idx] = 0xFFFFFFFFu;
    if (idx >= 77184) return;
    float val = 0.f;
    if (idx < 16128)        { int n = idx / 168,            k = idx - n * 168;            if (k < 156) val = w00[k * 96 + n]; }
    else if (idx < 26112)   { int t = idx - 16128, n = t / 104, k = t - n * 104;          if (k < 96)  val = w01[k * 96 + n]; }
    else if (idx < 36096)   { int t = idx - 26112, n = t / 104, k = t - n * 104;          if (k < 96)  val = w02[k * 96 + n]; }
    else if (idx < 52224)   { int t = idx - 36096, n = t / 168, k = t - n * 168;          if (k < 156) val = w10[k * 96 + n]; }
    else if (idx < 62208)   { int t = idx - 52224, n = t / 104, k = t - n * 104;          if (k < 96)  val = w11[k * 96 + n]; }
    else if (idx < 72192)   { int t = idx - 62208, n = t / 104, k = t - n * 104;          if (k < 96)  val = w12[k * 96 + n]; }
    else                    { int t = idx - 72192, n = t / 104, k = t - n * 104;          if (k < 96 && n < 45) val = pw[k * 45 + n]; }
    wsW[idx] = f2bf(val);
}

// ---------------- prepass: global min of base_c = org + ci*vox - q over all points ----------------
__global__ void decoder_prepass(const float* __restrict__ qc, const float* __restrict__ ext,
                                unsigned* __restrict__ keys) {
    __shared__ unsigned mk[3];
    int tid = threadIdx.x;
    int lane = tid & 63;
    if (tid < 3) mk[tid] = 0xFFFFFFFFu;
    __syncthreads();
    int p = blockIdx.x * 256 + tid;
    #pragma unroll
    for (int c = 0; c < 3; ++c) {
        float org = ext[c * CVOL];
        float vox = fabsf(ext[c * CVOL + 1057] - org);
        float q = qc[c * NQ + p];
        float nf = rintf((q - org) / vox);
        int ci = (int)nf; ci = ci < 0 ? 0 : (ci > 30 ? 30 : ci);
        float base = org + (float)ci * vox - q;
        for (int off = 32; off > 0; off >>= 1) base = fminf(base, __shfl_xor(base, off));
        if (lane == 0) atomicMin(&mk[c], encodeMin(base));
    }
    __syncthreads();
    if (tid < 3) atomicMin(&keys[tid], mk[tid]);
}

// ---------------- main fused kernel ----------------
__global__ __launch_bounds__(256, 2) void decoder_main(
    const ushort_t* __restrict__ cvT, const float* __restrict__ ext,
    const float* __restrict__ qvx, const float* __restrict__ qc,
    const float* __restrict__ b00, const float* __restrict__ b01, const float* __restrict__ b02,
    const float* __restrict__ b10, const float* __restrict__ b11, const float* __restrict__ b12,
    const float* __restrict__ pb, const ushort_t* __restrict__ wsW,
    const unsigned* __restrict__ minKeys, float* __restrict__ out)
{
    __shared__ ushort_t Xin[128 * SA];     // rows = (point, corner), cols = [h(96) | feats(60) | pad]
    __shared__ ushort_t Wstg[96 * SA];     // per-layer staged transposed weights
    __shared__ ushort_t Hhat[16 * SW];     // corner-blended h
    __shared__ float ptQ[3][16], ptBase[3][16], ptT[3][16];
    __shared__ int ptCI[3][16];
    __shared__ float wcorn[16][8];

    const int tid = threadIdx.x;
    const int lane = tid & 63;
    const int wv = tid >> 6;
    const int quad = lane >> 4;
    const int l16 = lane & 15;
    const int wm = wv & 1, wn = wv >> 1;   // 2x2 wave grid over (M-half, N-half)
    const int p0 = blockIdx.x * 16;

    // broadcast scalars
    float vox[3], org[3], lim[3], inv3v[3], qv[3], mrel[3][2];
    #pragma unroll
    for (int c = 0; c < 3; ++c) {
        org[c] = ext[c * CVOL];
        vox[c] = fabsf(ext[c * CVOL + 1057] - org[c]);
        lim[c] = -0.5f * vox[c] + 1e-7f;
        inv3v[c] = 1.0f / (1.5f * vox[c]);
        qv[c] = qvx[c];
        float mb = decodeMin(minKeys[c]);
        mrel[c][0] = fmaxf(mb, lim[c]);
        mrel[c][1] = fmaxf(mb + vox[c], lim[c]);
    }

    // per-point setup
    if (tid < 64) {
        int p = tid >> 2, c = tid & 3;
        if (c < 3) {
            float q = qc[c * NQ + p0 + p];
            float nf = rintf((q - org[c]) / vox[c]);   // RNE == jnp.round
            int ci = (int)nf; ci = ci < 0 ? 0 : (ci > 30 ? 30 : ci);
            float base = org[c] + (float)ci * vox[c] - q;
            float rel0 = fmaxf(base, lim[c]);
            float g = fminf(fmaxf((rel0 - 0.5f) * 2.0f, -1.0f + 1e-7f), 1.0f - 1e-7f);
            ptQ[c][p] = q; ptCI[c][p] = ci; ptBase[c][p] = base; ptT[c][p] = (g + 1.0f) * 0.5f;
        }
    }
    __syncthreads();

    // trilinear corner weights (NOTE reference's channel swap: i->t[2], j->t[1], k->t[0])
    if (tid < 128) {
        int p = tid >> 3, corner = tid & 7;
        int i = corner >> 2, j = (corner >> 1) & 1, k = corner & 1;
        float wx = i ? ptT[2][p] : 1.0f - ptT[2][p];
        float wy = j ? ptT[1][p] : 1.0f - ptT[1][p];
        float wz = k ? ptT[0][p] : 1.0f - ptT[0][p];
        wcorn[p][corner] = wx * wy * wz;
    }

    // gather (coalesced, bf16 cvT) + coord features; 2 threads per row
    {
        const int r = tid >> 1, h = tid & 1;
        const int p = r >> 3, corner = r & 7;
        const int i0 = corner >> 2, i1 = (corner >> 1) & 1, i2 = corner & 1;
        int io[3] = {i0, i1, i2};

        // h-part: 96 bf16 contiguous from cvT
        int cell = (ptCI[0][p] + i0) * 1024 + (ptCI[1][p] + i1) * 32 + ptCI[2][p] + i2;
        const uint4* src = (const uint4*)&cvT[cell * 96];
        uint4* dstX = (uint4*)&Xin[r * SA];
        #pragma unroll
        for (int cc = h * 6; cc < h * 6 + 6; ++cc) dstX[cc] = src[cc];

        // coord features
        float rn[3];
        #pragma unroll
        for (int c = 0; c < 3; ++c) {
            float rel = fmaxf(ptBase[c][p] + (float)io[c] * vox[c], lim[c]);
            rn[c] = (rel - mrel[c][io[c]]) * inv3v[c];
        }
        ushort_t* row = &Xin[r * SA];
        if (h == 0) {
            #pragma unroll
            for (int c = 0; c < 3; ++c) {
                row[96 + c]  = f2bf(qv[c]);
                row[99 + c]  = f2bf(org[c] + (float)(ptCI[c][p] + io[c]) * vox[c]);
                row[102 + c] = f2bf(ptQ[c][p]);
                row[105 + c] = f2bf(rn[c]);
            }
            #pragma unroll
            for (int z = 156; z < SA; ++z) row[z] = 0;
            #pragma unroll
            for (int m = 0; m < 8; ++m) {
                float s, co;
                sincospif(2.0f * rn[0] * FREQ[m], &s, &co);
                row[108 + m] = f2bf(s);
                row[116 + m] = f2bf(co);
            }
        } else {
            #pragma unroll
            for (int c = 1; c < 3; ++c) {
                #pragma unroll
                for (int m = 0; m < 8; ++m) {
                    float s, co;
                    sincospif(2.0f * rn[c] * FREQ[m], &s, &co);
                    row[108 + c * 16 + m] = f2bf(s);
                    row[108 + c * 16 + 8 + m] = f2bf(co);
                }
            }
        }
    }
    __syncthreads();

    // two skip blocks
    #pragma unroll 1
    for (int blk = 0; blk < 2; ++blk) {
        // snapshot h_old for the residual (blk0: after gather barrier; blk1: own epilogue values)
        float hold[4][3][4];
        #pragma unroll
        for (int mt = 0; mt < 4; ++mt)
            #pragma unroll
            for (int nt = 0; nt < 3; ++nt)
                #pragma unroll
                for (int r = 0; r < 4; ++r)
                    hold[mt][nt][r] = bf2f(Xin[(64 * wm + 16 * mt + quad * 4 + r) * SA + 48 * wn + 16 * nt + l16]);

        #pragma unroll 1
        for (int l = 0; l < 3; ++l) {
            {   // stage this layer's weights (prev layer's readers already past their read-done barrier)
                int off = (blk ? 36096 : 0) + (l == 1 ? 16128 : (l == 2 ? 26112 : 0));
                int nd = l ? 4992 : 8064;
                const unsigned* s = (const unsigned*)(wsW + off);
                unsigned* d = (unsigned*)Wstg;
                for (int f = tid; f < nd; f += 256) d[f] = s[f];
            }
            __syncthreads();   // publishes staged weights AND prev layer's Xin write-back

            const int nkc = l ? 3 : 5;
            const int sw = l ? SW : SA;
            floatx4 acc[4][3];
            #pragma unroll
            for (int mt = 0; mt < 4; ++mt)
                #pragma unroll
                for (int nt = 0; nt < 3; ++nt) acc[mt][nt] = (floatx4){0.f, 0.f, 0.f, 0.f};

            for (int kc = 0; kc < nkc; ++kc) {
                short8 a[4];
                #pragma unroll
                for (int mt = 0; mt < 4; ++mt)
                    a[mt] = *(const short8*)&Xin[(64 * wm + 16 * mt + l16) * SA + kc * 32 + quad * 8];
                #pragma unroll
                for (int nt = 0; nt < 3; ++nt) {
                    short8 bfrag = *(const short8*)&Wstg[(48 * wn + 16 * nt + l16) * sw + kc * 32 + quad * 8];
                    #pragma unroll
                    for (int mt = 0; mt < 4; ++mt)
                        acc[mt][nt] = __builtin_amdgcn_mfma_f32_16x16x32_bf16(a[mt], bfrag, acc[mt][nt], 0, 0, 0);
                }
            }

            const float* bias = (l == 0) ? (blk ? b10 : b00) : (l == 1) ? (blk ? b11 : b01) : (blk ? b12 : b02);
            #pragma unroll
            for (int nt = 0; nt < 3; ++nt) {
                float bv = bias[48 * wn + 16 * nt + l16];
                #pragma unroll
                for (int mt = 0; mt < 4; ++mt)
                    #pragma unroll
                    for (int r = 0; r < 4; ++r) {
                        float z = acc[mt][nt][r] + bv;
                        float s = z * __builtin_amdgcn_rcpf(1.0f + __expf(-z));   // silu, fast rcp
                        if (l == 2) s += hold[mt][nt][r];                          // residual
                        acc[mt][nt][r] = s;
                    }
            }
            __syncthreads();   // everyone's Wstg/Xin reads done before overwriting
            #pragma unroll
            for (int mt = 0; mt < 4; ++mt)
                #pragma unroll
                for (int nt = 0; nt < 3; ++nt)
                    #pragma unroll
                    for (int r = 0; r < 4; ++r)
                        Xin[(64 * wm + 16 * mt + quad * 4 + r) * SA + 48 * wn + 16 * nt + l16] = f2bf(acc[mt][nt][r]);
        }
    }
    __syncthreads();   // publish final h

    // blend 8 corners into hhat (post layer linear, trilinear weights sum to 1 -> blend first)
    {
        int p = tid >> 4, s6 = (tid & 15) * 6;
        float w8[8];
        #pragma unroll
        for (int c = 0; c < 8; ++c) w8[c] = wcorn[p][c];
        #pragma unroll
        for (int cc = 0; cc < 6; ++cc) {
            int col = s6 + cc;
            float sum = 0.f;
            #pragma unroll
            for (int c = 0; c < 8; ++c) sum += w8[c] * bf2f(Xin[(p * 8 + c) * SA + col]);
            Hhat[p * SW + col] = f2bf(sum);
        }
    }
    {   // stage post weights (all prior Wstg readers are past their read-done barrier)
        const unsigned* s = (const unsigned*)(wsW + 72192);
        unsigned* d = (unsigned*)Wstg;
        for (int f = tid; f < 2496; f += 256) d[f] = s[f];
    }
    __syncthreads();

    // post GEMM: 16 points x 48(45) out channels, waves 0..2 take one n-tile each
    if (wv < 3) {
        floatx4 acc = (floatx4){0.f, 0.f, 0.f, 0.f};
        #pragma unroll
        for (int kc = 0; kc < 3; ++kc) {
            short8 a = *(const short8*)&Hhat[l16 * SW + kc * 32 + quad * 8];
            short8 bfrag = *(const short8*)&Wstg[(16 * wv + l16) * SW + kc * 32 + quad * 8];
            acc = __builtin_amdgcn_mfma_f32_16x16x32_bf16(a, bfrag, acc, 0, 0, 0);
        }
        int n = 16 * wv + l16;
        if (n < 45) {
            float bv = pb[n];
            float4 v;
            v.x = acc[0] + bv; v.y = acc[1] + bv; v.z = acc[2] + bv; v.w = acc[3] + bv;
            *(float4*)&out[n * NQ + p0 + quad * 4] = v;
        }
    }
}

extern "C" void kernel_launch(void* const* d_in, const int* in_sizes, int n_in,
                              void* d_out, int out_size, void* d_ws, size_t ws_size,
                              hipStream_t stream) {
    (void)in_sizes; (void)n_in; (void)out_size; (void)ws_size;
    const float* cv  = (const float*)d_in[0];
    const float* ext = (const float*)d_in[1];
    const float* qvx = (const float*)d_in[2];
    const float* qc  = (const float*)d_in[3];
    const float* w00 = (const float*)d_in[4];
    const float* b00 = (const float*)d_in[5];
    const float* w01 = (const float*)d_in[6];
    const float* b01 = (const float*)d_in[7];
    const float* w02 = (const float*)d_in[8];
    const float* b02 = (const float*)d_in[9];
    const float* w10 = (const float*)d_in[10];
    const float* b10 = (const float*)d_in[11];
    const float* w11 = (const float*)d_in[12];
    const float* b11 = (const float*)d_in[13];
    const float* w12 = (const float*)d_in[14];
    const float* b12 = (const float*)d_in[15];
    const float* pw  = (const float*)d_in[16];
    const float* pb  = (const float*)d_in[17];

    unsigned* keys = (unsigned*)d_ws;                         // 3 uint min-keys
    ushort_t* wsW  = (ushort_t*)((char*)d_ws + 64);           // 77184 bf16 transposed weights
    ushort_t* cvT  = (ushort_t*)((char*)d_ws + 163840);       // 32768*96 bf16 cell-major context

    decoder_txp<<<256, 256, 0, stream>>>(cv, cvT);
    decoder_prep<<<302, 256, 0, stream>>>(w00, w01, w02, w10, w11, w12, pw, wsW, keys);
    decoder_prepass<<<432, 256, 0, stream>>>(qc, ext, keys);
    decoder_main<<<6912, 256, 0, stream>>>(cvT, ext, qvx, qc,
                                           b00, b01, b02, b10, b11, b12,
                                           pb, wsW, keys, (float*)d_out);
}

// Round 4
// 377.393 us; speedup vs baseline: 2.8947x; 1.4761x over previous
//
#include <hip/hip_runtime.h>
#include <hip/hip_bf16.h>

typedef unsigned short ushort_t;
typedef short short8 __attribute__((ext_vector_type(8)));
typedef float floatx4 __attribute__((ext_vector_type(4)));

#define SA 168   // Xin row stride in bf16 elems: 336B = 21*16 (16B-aligned, 2-way banks = free)
#define SW 104   // Hhat stride: 208B = 13*16
#define NQ 110592
#define CVOL 32768

// swizzled-weight element offsets in wsW (see decoder_prep)
#define L0A 0
#define L1A 15360
#define L2A 24576
#define L0B 33792
#define L1B 49152
#define L2B 58368
#define PST 67584
#define WTOT 72192

#if __has_builtin(__builtin_amdgcn_sinf) && __has_builtin(__builtin_amdgcn_cosf) && __has_builtin(__builtin_amdgcn_fractf)
#define FAST_SINCOS 1
#else
#define FAST_SINCOS 0
#endif

__device__ __forceinline__ float bf2f(ushort_t u) { return __uint_as_float(((unsigned)u) << 16); }
__device__ __forceinline__ ushort_t f2bf(float f) {
    unsigned u = __float_as_uint(f);
    unsigned r = (u + 0x7fffu + ((u >> 16) & 1u)) >> 16;
    return (ushort_t)r;
}
__device__ __forceinline__ unsigned encodeMin(float x) {
    unsigned u = __float_as_uint(x);
    return (u & 0x80000000u) ? ~u : (u | 0x80000000u);
}
__device__ __forceinline__ float decodeMin(unsigned key) {
    unsigned u = (key & 0x80000000u) ? (key ^ 0x80000000u) : ~key;
    return __uint_as_float(u);
}

__device__ __constant__ float FREQ[8] = {
    1.0f, 1.2228445f, 1.4953488f, 1.8285791f,
    2.2360680f, 2.7343640f, 3.3437015f, 4.0888269f
};

// ---------------- transpose cv [96][32768] fp32 -> cvT [32768][96] bf16 ----------------
__global__ void decoder_txp(const float* __restrict__ cv, ushort_t* __restrict__ cvT) {
    __shared__ ushort_t ld[128 * SW];
    int tid = threadIdx.x;
    int base = blockIdx.x * 128;
    int cl = tid & 127, h = tid >> 7;
    #pragma unroll 4
    for (int ch = h * 48; ch < h * 48 + 48; ++ch)
        ld[cl * SW + ch] = f2bf(cv[ch * CVOL + base + cl]);
    __syncthreads();
    #pragma unroll
    for (int it = 0; it < 6; ++it) {
        int idx = it * 256 + tid;
        int r = idx / 12, c = idx - r * 12;
        *(uint4*)&cvT[(base + r) * 96 + c * 8] = *(const uint4*)&ld[r * SW + c * 8];
    }
}

// ---------------- prep: swizzle fp32 weights into per-wave fragment order (bf16) ----------------
// layout per layer: [n-tile t][kc][lane(64)][j(8)]; element = W[kc*32+(lane>>4)*8+j][t*16+(lane&15)]
__global__ void decoder_prep(const float* __restrict__ w00, const float* __restrict__ w01,
                             const float* __restrict__ w02, const float* __restrict__ w10,
                             const float* __restrict__ w11, const float* __restrict__ w12,
                             const float* __restrict__ pw, ushort_t* __restrict__ wsW,
                             unsigned* __restrict__ keys) {
    int idx = blockIdx.x * 256 + threadIdx.x;
    if (idx < 3) keys[idx] = 0xFFFFFFFFu;
    if (idx >= WTOT) return;
    const float* W; int K, N, fo, nkc, off;
    if (idx < L1A)      { W = w00; K = 156; N = 96; fo = 96; nkc = 5; off = L0A; }
    else if (idx < L2A) { W = w01; K = 96;  N = 96; fo = 96; nkc = 3; off = L1A; }
    else if (idx < L0B) { W = w02; K = 96;  N = 96; fo = 96; nkc = 3; off = L2A; }
    else if (idx < L1B) { W = w10; K = 156; N = 96; fo = 96; nkc = 5; off = L0B; }
    else if (idx < L2B) { W = w11; K = 96;  N = 96; fo = 96; nkc = 3; off = L1B; }
    else if (idx < PST) { W = w12; K = 96;  N = 96; fo = 96; nkc = 3; off = L2B; }
    else                { W = pw;  K = 96;  N = 45; fo = 45; nkc = 3; off = PST; }
    int li = idx - off;
    int j = li & 7, lane = (li >> 3) & 63, chunk = li >> 9;
    int kc = chunk % nkc, t = chunk / nkc;
    int k = kc * 32 + (lane >> 4) * 8 + j;
    int n = t * 16 + (lane & 15);
    wsW[idx] = (k < K && n < N) ? f2bf(W[k * fo + n]) : (ushort_t)0;
}

// ---------------- prepass: global min of base_c = org + ci*vox - q over all points ----------------
__global__ void decoder_prepass(const float* __restrict__ qc, const float* __restrict__ ext,
                                unsigned* __restrict__ keys) {
    __shared__ unsigned mk[3];
    int tid = threadIdx.x;
    int lane = tid & 63;
    if (tid < 3) mk[tid] = 0xFFFFFFFFu;
    __syncthreads();
    int p = blockIdx.x * 256 + tid;
    #pragma unroll
    for (int c = 0; c < 3; ++c) {
        float org = ext[c * CVOL];
        float vox = fabsf(ext[c * CVOL + 1057] - org);
        float q = qc[c * NQ + p];
        float nf = rintf((q - org) / vox);
        int ci = (int)nf; ci = ci < 0 ? 0 : (ci > 30 ? 30 : ci);
        float base = org + (float)ci * vox - q;
        for (int off = 32; off > 0; off >>= 1) base = fminf(base, __shfl_xor(base, off));
        if (lane == 0) atomicMin(&mk[c], encodeMin(base));
    }
    __syncthreads();
    if (tid < 3) atomicMin(&keys[tid], mk[tid]);
}

// B-fragments straight from global (pre-swizzled, coalesced 1KB/wave), A from LDS
template <int NKC>
__device__ __forceinline__ void layer_gemm(const ushort_t* __restrict__ wb,
                                           const ushort_t* XinP, int wn3, int lane8, int quad8,
                                           floatx4 acc[4][3]) {
    short8 bfr[NKC][3];
    #pragma unroll
    for (int nt = 0; nt < 3; ++nt)
        #pragma unroll
        for (int kc = 0; kc < NKC; ++kc)
            bfr[kc][nt] = *(const short8*)&wb[(((wn3 + nt) * NKC + kc) << 9) + lane8];
    #pragma unroll
    for (int mt = 0; mt < 4; ++mt)
        #pragma unroll
        for (int nt = 0; nt < 3; ++nt) acc[mt][nt] = (floatx4){0.f, 0.f, 0.f, 0.f};
    #pragma unroll
    for (int kc = 0; kc < NKC; ++kc) {
        short8 a[4];
        #pragma unroll
        for (int mt = 0; mt < 4; ++mt)
            a[mt] = *(const short8*)&XinP[mt * 16 * SA + kc * 32 + quad8];
        #pragma unroll
        for (int nt = 0; nt < 3; ++nt)
            #pragma unroll
            for (int mt = 0; mt < 4; ++mt)
                acc[mt][nt] = __builtin_amdgcn_mfma_f32_16x16x32_bf16(a[mt], bfr[kc][nt], acc[mt][nt], 0, 0, 0);
    }
}

// ---------------- main fused kernel ----------------
__global__ __launch_bounds__(256, 3) void decoder_main(
    const ushort_t* __restrict__ cvT, const float* __restrict__ ext,
    const float* __restrict__ qvx, const float* __restrict__ qc,
    const float* __restrict__ b00, const float* __restrict__ b01, const float* __restrict__ b02,
    const float* __restrict__ b10, const float* __restrict__ b11, const float* __restrict__ b12,
    const float* __restrict__ pb, const ushort_t* __restrict__ wsW,
    const unsigned* __restrict__ minKeys, float* __restrict__ out)
{
    __shared__ ushort_t Xin[128 * SA];     // rows = (point, corner), cols = [h(96) | feats(60) | pad]
    __shared__ ushort_t Hhat[16 * SW];     // corner-blended h
    __shared__ float ptQ[3][16], ptBase[3][16], ptT[3][16];
    __shared__ int ptCI[3][16];
    __shared__ float wcorn[16][8];

    const int tid = threadIdx.x;
    const int lane = tid & 63;
    const int wv = tid >> 6;
    const int quad = lane >> 4;
    const int l16 = lane & 15;
    const int wm = wv & 1, wn = wv >> 1;   // 2x2 wave grid over (M-half, N-half)
    const int wn3 = wn * 3, lane8 = lane << 3, quad8 = quad * 8;
    const int p0 = blockIdx.x * 16;

    // broadcast scalars
    float vox[3], org[3], lim[3], inv3v[3], qv[3], mrel[3][2];
    #pragma unroll
    for (int c = 0; c < 3; ++c) {
        org[c] = ext[c * CVOL];
        vox[c] = fabsf(ext[c * CVOL + 1057] - org[c]);
        lim[c] = -0.5f * vox[c] + 1e-7f;
        inv3v[c] = 1.0f / (1.5f * vox[c]);
        qv[c] = qvx[c];
        float mb = decodeMin(minKeys[c]);
        mrel[c][0] = fmaxf(mb, lim[c]);
        mrel[c][1] = fmaxf(mb + vox[c], lim[c]);
    }

    // per-point setup
    if (tid < 64) {
        int p = tid >> 2, c = tid & 3;
        if (c < 3) {
            float q = qc[c * NQ + p0 + p];
            float nf = rintf((q - org[c]) / vox[c]);   // RNE == jnp.round
            int ci = (int)nf; ci = ci < 0 ? 0 : (ci > 30 ? 30 : ci);
            float base = org[c] + (float)ci * vox[c] - q;
            float rel0 = fmaxf(base, lim[c]);
            float g = fminf(fmaxf((rel0 - 0.5f) * 2.0f, -1.0f + 1e-7f), 1.0f - 1e-7f);
            ptQ[c][p] = q; ptCI[c][p] = ci; ptBase[c][p] = base; ptT[c][p] = (g + 1.0f) * 0.5f;
        }
    }
    __syncthreads();

    // trilinear corner weights (NOTE reference's channel swap: i->t[2], j->t[1], k->t[0])
    if (tid < 128) {
        int p = tid >> 3, corner = tid & 7;
        int i = corner >> 2, j = (corner >> 1) & 1, k = corner & 1;
        float wx = i ? ptT[2][p] : 1.0f - ptT[2][p];
        float wy = j ? ptT[1][p] : 1.0f - ptT[1][p];
        float wz = k ? ptT[0][p] : 1.0f - ptT[0][p];
        wcorn[p][corner] = wx * wy * wz;
    }

    // gather (coalesced, bf16 cvT) + coord features; 2 threads per row
    {
        const int r = tid >> 1, h = tid & 1;
        const int p = r >> 3, corner = r & 7;
        const int i0 = corner >> 2, i1 = (corner >> 1) & 1, i2 = corner & 1;
        int io[3] = {i0, i1, i2};

        int cell = (ptCI[0][p] + i0) * 1024 + (ptCI[1][p] + i1) * 32 + ptCI[2][p] + i2;
        const uint4* src = (const uint4*)&cvT[cell * 96];
        uint4* dstX = (uint4*)&Xin[r * SA];
        #pragma unroll
        for (int cc = h * 6; cc < h * 6 + 6; ++cc) dstX[cc] = src[cc];

        float rn[3];
        #pragma unroll
        for (int c = 0; c < 3; ++c) {
            float rel = fmaxf(ptBase[c][p] + (float)io[c] * vox[c], lim[c]);
            rn[c] = (rel - mrel[c][io[c]]) * inv3v[c];
        }
        ushort_t* row = &Xin[r * SA];
        if (h == 0) {
            #pragma unroll
            for (int c = 0; c < 3; ++c) {
                row[96 + c]  = f2bf(qv[c]);
                row[99 + c]  = f2bf(org[c] + (float)(ptCI[c][p] + io[c]) * vox[c]);
                row[102 + c] = f2bf(ptQ[c][p]);
                row[105 + c] = f2bf(rn[c]);
            }
            #pragma unroll
            for (int z = 156; z < SA; ++z) row[z] = 0;
            #pragma unroll
            for (int m = 0; m < 8; ++m) {
                float ang = rn[0] * FREQ[m];            // revolutions: sin(2*pi*ang)
#if FAST_SINCOS
                float fr = __builtin_amdgcn_fractf(ang);
                row[108 + m] = f2bf(__builtin_amdgcn_sinf(fr));
                row[116 + m] = f2bf(__builtin_amdgcn_cosf(fr));
#else
                float s, co; sincospif(2.0f * ang, &s, &co);
                row[108 + m] = f2bf(s); row[116 + m] = f2bf(co);
#endif
            }
        } else {
            #pragma unroll
            for (int c = 1; c < 3; ++c) {
                #pragma unroll
                for (int m = 0; m < 8; ++m) {
                    float ang = rn[c] * FREQ[m];
#if FAST_SINCOS
                    float fr = __builtin_amdgcn_fractf(ang);
                    row[108 + c * 16 + m] = f2bf(__builtin_amdgcn_sinf(fr));
                    row[108 + c * 16 + 8 + m] = f2bf(__builtin_amdgcn_cosf(fr));
#else
                    float s, co; sincospif(2.0f * ang, &s, &co);
                    row[108 + c * 16 + m] = f2bf(s);
                    row[108 + c * 16 + 8 + m] = f2bf(co);
#endif
                }
            }
        }
    }
    __syncthreads();

    const ushort_t* XinP = &Xin[(64 * wm + l16) * SA];
    const int wboff[2][3] = {{L0A, L1A, L2A}, {L0B, L1B, L2B}};
    const float* const bptr[2][3] = {{b00, b01, b02}, {b10, b11, b12}};
    float hold[4][3][4];
    floatx4 acc[4][3];

    #pragma unroll
    for (int blk = 0; blk < 2; ++blk) {
        if (blk == 0) {   // residual snapshot from gather; blk1 carries it in registers
            #pragma unroll
            for (int mt = 0; mt < 4; ++mt)
                #pragma unroll
                for (int nt = 0; nt < 3; ++nt)
                    #pragma unroll
                    for (int r = 0; r < 4; ++r)
                        hold[mt][nt][r] = bf2f(Xin[(64 * wm + 16 * mt + quad * 4 + r) * SA + 48 * wn + 16 * nt + l16]);
        }

        #pragma unroll
        for (int l = 0; l < 3; ++l) {
            if (l == 0) layer_gemm<5>(wsW + wboff[blk][0], XinP, wn3, lane8, quad8, acc);
            else        layer_gemm<3>(wsW + wboff[blk][l], XinP, wn3, lane8, quad8, acc);

            const float* bias = bptr[blk][l];
            ushort_t hb[4][3][4];
            #pragma unroll
            for (int nt = 0; nt < 3; ++nt) {
                float bv = bias[48 * wn + 16 * nt + l16];
                #pragma unroll
                for (int mt = 0; mt < 4; ++mt)
                    #pragma unroll
                    for (int r = 0; r < 4; ++r) {
                        float z = acc[mt][nt][r] + bv;
                        float s = z * __builtin_amdgcn_rcpf(1.0f + __expf(-z));   // silu
                        if (l == 2) {
                            s += hold[mt][nt][r];                                  // residual
                            ushort_t u = f2bf(s);
                            hb[mt][nt][r] = u;
                            hold[mt][nt][r] = bf2f(u);                             // carry to next blk
                        } else {
                            hb[mt][nt][r] = f2bf(s);
                        }
                    }
            }
            __syncthreads();   // all A-reads of this layer done before overwrite
            #pragma unroll
            for (int mt = 0; mt < 4; ++mt)
                #pragma unroll
                for (int nt = 0; nt < 3; ++nt)
                    #pragma unroll
                    for (int r = 0; r < 4; ++r)
                        Xin[(64 * wm + 16 * mt + quad * 4 + r) * SA + 48 * wn + 16 * nt + l16] = hb[mt][nt][r];
            __syncthreads();   // writes visible before next layer's A-reads
        }
    }

    // blend 8 corners into hhat (post layer linear, trilinear weights sum to 1 -> blend first)
    {
        int p = tid >> 4, s6 = (tid & 15) * 6;
        float w8[8];
        #pragma unroll
        for (int c = 0; c < 8; ++c) w8[c] = wcorn[p][c];
        #pragma unroll
        for (int cc = 0; cc < 6; ++cc) {
            int col = s6 + cc;
            float sum = 0.f;
            #pragma unroll
            for (int c = 0; c < 8; ++c) sum += w8[c] * bf2f(Xin[(p * 8 + c) * SA + col]);
            Hhat[p * SW + col] = f2bf(sum);
        }
    }
    __syncthreads();

    // post GEMM: 16 points x 48(45) out channels, waves 0..2 take one n-tile each
    if (wv < 3) {
        const ushort_t* wb = wsW + PST;
        floatx4 pacc = (floatx4){0.f, 0.f, 0.f, 0.f};
        #pragma unroll
        for (int kc = 0; kc < 3; ++kc) {
            short8 a = *(const short8*)&Hhat[l16 * SW + kc * 32 + quad8];
            short8 bfrag = *(const short8*)&wb[(((wv * 3) + kc) << 9) + lane8];
            pacc = __builtin_amdgcn_mfma_f32_16x16x32_bf16(a, bfrag, pacc, 0, 0, 0);
        }
        int n = 16 * wv + l16;
        if (n < 45) {
            float bv = pb[n];
            float4 v;
            v.x = pacc[0] + bv; v.y = pacc[1] + bv; v.z = pacc[2] + bv; v.w = pacc[3] + bv;
            *(float4*)&out[n * NQ + p0 + quad * 4] = v;
        }
    }
}

extern "C" void kernel_launch(void* const* d_in, const int* in_sizes, int n_in,
                              void* d_out, int out_size, void* d_ws, size_t ws_size,
                              hipStream_t stream) {
    (void)in_sizes; (void)n_in; (void)out_size; (void)ws_size;
    const float* cv  = (const float*)d_in[0];
    const float* ext = (const float*)d_in[1];
    const float* qvx = (const float*)d_in[2];
    const float* qc  = (const float*)d_in[3];
    const float* w00 = (const float*)d_in[4];
    const float* b00 = (const float*)d_in[5];
    const float* w01 = (const float*)d_in[6];
    const float* b01 = (const float*)d_in[7];
    const float* w02 = (const float*)d_in[8];
    const float* b02 = (const float*)d_in[9];
    const float* w10 = (const float*)d_in[10];
    const float* b10 = (const float*)d_in[11];
    const float* w11 = (const float*)d_in[12];
    const float* b11 = (const float*)d_in[13];
    const float* w12 = (const float*)d_in[14];
    const float* b12 = (const float*)d_in[15];
    const float* pw  = (const float*)d_in[16];
    const float* pb  = (const float*)d_in[17];

    unsigned* keys = (unsigned*)d_ws;                         // 3 uint min-keys
    ushort_t* wsW  = (ushort_t*)((char*)d_ws + 64);           // 72192 bf16 swizzled weights
    ushort_t* cvT  = (ushort_t*)((char*)d_ws + 163840);       // 32768*96 bf16 cell-major context

    decoder_txp<<<256, 256, 0, stream>>>(cv, cvT);
    decoder_prep<<<282, 256, 0, stream>>>(w00, w01, w02, w10, w11, w12, pw, wsW, keys);
    decoder_prepass<<<432, 256, 0, stream>>>(qc, ext, keys);
    decoder_main<<<6912, 256, 0, stream>>>(cvT, ext, qvx, qc,
                                           b00, b01, b02, b10, b11, b12,
                                           pb, wsW, keys, (float*)d_out);
}

// Round 6
// 356.728 us; speedup vs baseline: 3.0624x; 1.0579x over previous
//
#include <hip/hip_runtime.h>
#include <hip/hip_bf16.h>

typedef unsigned short ushort_t;
typedef short short8 __attribute__((ext_vector_type(8)));
typedef short shrt4 __attribute__((ext_vector_type(4)));
typedef unsigned short ush4 __attribute__((ext_vector_type(4)));
typedef unsigned int uintx2 __attribute__((ext_vector_type(2)));
typedef float floatx4 __attribute__((ext_vector_type(4)));

#define SA 168   // Xin row stride in bf16 elems: 336B = 21*16
#define SW 104   // Hhat stride
#define NQ 110592
#define CVOL 32768

// wsW bf16 element offsets
#define L0A   0        // blk0 l0 weights, 16x16x32 A-layout [mt6][kc5][lane][8]
#define L0B   15360    // blk1 l0
#define A1_00 30720    // blk0 l1 weights, 16x16x16 A-layout [mt6][kp3][lane][kl2*4+i]
#define A1_01 39936    // blk0 l2
#define A1_10 49152    // blk1 l1
#define A1_11 58368    // blk1 l2
#define PST   67584    // post weights, 16x16x32 B-layout (unchanged)
#define WTOT  72192
#define BTOT  9216     // bias floats, C-layout [layer6][mt6][lane][r4]

// ws byte offsets
#define WSW_OFF  64
#define BIAS_OFF 147456
#define CVT_OFF  196608

// Device pass: the real gfx950 builtin (bf16_1k spelling — verified by round-5 device
// pass compiling clean). Host pass: type-correct no-op; host never runs device code.
#if defined(__HIP_DEVICE_COMPILE__)
#define MFMA16(A, B, C) __builtin_amdgcn_mfma_f32_16x16x16bf16_1k(A, B, C, 0, 0, 0)
#else
#define MFMA16(A, B, C) (C)
#endif

#if defined(__HIP_DEVICE_COMPILE__) && __has_builtin(__builtin_amdgcn_sinf) && __has_builtin(__builtin_amdgcn_cosf) && __has_builtin(__builtin_amdgcn_fractf)
#define FAST_SINCOS 1
#else
#define FAST_SINCOS 0
#endif

__device__ __forceinline__ float bf2f(ushort_t u) { return __uint_as_float(((unsigned)u) << 16); }
__device__ __forceinline__ ushort_t f2bf(float f) {
    unsigned u = __float_as_uint(f);
    unsigned r = (u + 0x7fffu + ((u >> 16) & 1u)) >> 16;
    return (ushort_t)r;
}
__device__ __forceinline__ shrt4 pk4(floatx4 v) {
    uintx2 u;
    u[0] = (unsigned)f2bf(v[0]) | ((unsigned)f2bf(v[1]) << 16);
    u[1] = (unsigned)f2bf(v[2]) | ((unsigned)f2bf(v[3]) << 16);
    return __builtin_bit_cast(shrt4, u);
}
__device__ __forceinline__ unsigned encodeMin(float x) {
    unsigned u = __float_as_uint(x);
    return (u & 0x80000000u) ? ~u : (u | 0x80000000u);
}
__device__ __forceinline__ float decodeMin(unsigned key) {
    unsigned u = (key & 0x80000000u) ? (key ^ 0x80000000u) : ~key;
    return __uint_as_float(u);
}

__device__ __constant__ float FREQ[8] = {
    1.0f, 1.2228445f, 1.4953488f, 1.8285791f,
    2.2360680f, 2.7343640f, 3.3437015f, 4.0888269f
};

// ---------------- transpose cv [96][32768] fp32 -> cvT [32768][96] bf16 ----------------
__global__ void decoder_txp(const float* __restrict__ cv, ushort_t* __restrict__ cvT) {
    __shared__ ushort_t ld[128 * SW];
    int tid = threadIdx.x;
    int base = blockIdx.x * 128;
    int cl = tid & 127, h = tid >> 7;
    #pragma unroll 4
    for (int ch = h * 48; ch < h * 48 + 48; ++ch)
        ld[cl * SW + ch] = f2bf(cv[ch * CVOL + base + cl]);
    __syncthreads();
    #pragma unroll
    for (int it = 0; it < 6; ++it) {
        int idx = it * 256 + tid;
        int r = idx / 12, c = idx - r * 12;
        *(uint4*)&cvT[(base + r) * 96 + c * 8] = *(const uint4*)&ld[r * SW + c * 8];
    }
}

// ---------------- prep: swizzle weights (A-layouts) + biases (C-layout fp32) ----------------
__global__ void decoder_prep(const float* __restrict__ w00, const float* __restrict__ b00,
                             const float* __restrict__ w01, const float* __restrict__ b01,
                             const float* __restrict__ w02, const float* __restrict__ b02,
                             const float* __restrict__ w10, const float* __restrict__ b10,
                             const float* __restrict__ w11, const float* __restrict__ b11,
                             const float* __restrict__ w12, const float* __restrict__ b12,
                             const float* __restrict__ pw, ushort_t* __restrict__ wsW,
                             float* __restrict__ biasF, unsigned* __restrict__ keys) {
    int idx = blockIdx.x * 256 + threadIdx.x;
    if (idx < 3) keys[idx] = 0xFFFFFFFFu;
    if (idx >= WTOT + BTOT) return;
    if (idx >= WTOT) {            // biases, fp32, C-layout
        int t = idx - WTOT;
        int layer = t / 1536, rem = t - layer * 1536;
        int mt = rem >> 8, l2i = rem & 255;
        int lane = l2i >> 2, r = l2i & 3;
        int m = mt * 16 + (lane >> 4) * 4 + r;
        const float* B = layer == 0 ? b00 : layer == 1 ? b01 : layer == 2 ? b02
                       : layer == 3 ? b10 : layer == 4 ? b11 : b12;
        biasF[t] = B[m];
        return;
    }
    ushort_t v = 0;
    if (idx < A1_00) {            // layer-0 weights: 16x16x32 A-layout
        const float* W = (idx < L0B) ? w00 : w10;
        int li = idx - ((idx < L0B) ? L0A : L0B);
        int j = li & 7, lane = (li >> 3) & 63, chunk = li >> 9;
        int kc = chunk % 5, mt = chunk / 5;
        int k = kc * 32 + (lane >> 4) * 8 + j;
        int m = mt * 16 + (lane & 15);
        if (k < 156) v = f2bf(W[k * 96 + m]);
    } else if (idx < PST) {       // layer-1/2 weights: 16x16x16 A-layout, kc-pairs packed
        const float* W = idx < A1_01 ? w01 : idx < A1_10 ? w02 : idx < A1_11 ? w11 : w12;
        int off = idx < A1_01 ? A1_00 : idx < A1_10 ? A1_01 : idx < A1_11 ? A1_10 : A1_11;
        int li = idx - off;
        int i = li & 3, kl = (li >> 2) & 1, lane = (li >> 3) & 63, chunk = li >> 9;
        int kp = chunk % 3, mt = chunk / 3;
        int k = (kp * 2 + kl) * 16 + (lane >> 4) * 4 + i;
        int m = mt * 16 + (lane & 15);
        v = f2bf(W[k * 96 + m]);
    } else {                      // post weights: 16x16x32 B-layout (unchanged)
        int li = idx - PST;
        int j = li & 7, lane = (li >> 3) & 63, chunk = li >> 9;
        int kc = chunk % 3, t = chunk / 3;
        int k = kc * 32 + (lane >> 4) * 8 + j;
        int n = t * 16 + (lane & 15);
        if (n < 45) v = f2bf(pw[k * 45 + n]);
    }
    wsW[idx] = v;
}

// ---------------- prepass: global min of base_c = org + ci*vox - q over all points ----------------
__global__ void decoder_prepass(const float* __restrict__ qc, const float* __restrict__ ext,
                                unsigned* __restrict__ keys) {
    __shared__ unsigned mk[3];
    int tid = threadIdx.x;
    int lane = tid & 63;
    if (tid < 3) mk[tid] = 0xFFFFFFFFu;
    __syncthreads();
    int p = blockIdx.x * 256 + tid;
    #pragma unroll
    for (int c = 0; c < 3; ++c) {
        float org = ext[c * CVOL];
        float vox = fabsf(ext[c * CVOL + 1057] - org);
        float q = qc[c * NQ + p];
        float nf = rintf((q - org) / vox);
        int ci = (int)nf; ci = ci < 0 ? 0 : (ci > 30 ? 30 : ci);
        float base = org + (float)ci * vox - q;
        for (int off = 32; off > 0; off >>= 1) base = fminf(base, __shfl_xor(base, off));
        if (lane == 0) atomicMin(&mk[c], encodeMin(base));
    }
    __syncthreads();
    if (tid < 3) atomicMin(&keys[tid], mk[tid]);
}

// ---------------- main fused kernel ----------------
__global__ __launch_bounds__(256, 3) void decoder_main(
    const ushort_t* __restrict__ cvT, const float* __restrict__ ext,
    const float* __restrict__ qvx, const float* __restrict__ qc,
    const float* __restrict__ pb, const ushort_t* __restrict__ wsW,
    const float* __restrict__ biasF,
    const unsigned* __restrict__ minKeys, float* __restrict__ out)
{
    __shared__ ushort_t Xin[128 * SA];     // rows = batch (point,corner), cols = [h(96)|feats(60)|pad]
    __shared__ ushort_t Hhat[16 * SW];
    __shared__ float ptQ[3][16], ptBase[3][16], ptT[3][16];
    __shared__ int ptCI[3][16];
    __shared__ float wcorn[16][8];

    const int tid = threadIdx.x;
    const int lane = tid & 63;
    const int wv = tid >> 6;
    const int quad = lane >> 4;
    const int l16 = lane & 15;
    const int lane8 = lane << 3, quad8 = quad * 8, quad4 = quad * 4;
    const int p0 = blockIdx.x * 16;
    const int col0 = wv * 32;              // wave-private batch columns [col0, col0+32)

    // broadcast scalars
    float vox[3], org[3], lim[3], inv3v[3], qv[3], mrel[3][2];
    #pragma unroll
    for (int c = 0; c < 3; ++c) {
        org[c] = ext[c * CVOL];
        vox[c] = fabsf(ext[c * CVOL + 1057] - org[c]);
        lim[c] = -0.5f * vox[c] + 1e-7f;
        inv3v[c] = 1.0f / (1.5f * vox[c]);
        qv[c] = qvx[c];
        float mb = decodeMin(minKeys[c]);
        mrel[c][0] = fmaxf(mb, lim[c]);
        mrel[c][1] = fmaxf(mb + vox[c], lim[c]);
    }

    // per-point setup
    if (tid < 64) {
        int p = tid >> 2, c = tid & 3;
        if (c < 3) {
            float q = qc[c * NQ + p0 + p];
            float nf = rintf((q - org[c]) / vox[c]);   // RNE == jnp.round
            int ci = (int)nf; ci = ci < 0 ? 0 : (ci > 30 ? 30 : ci);
            float base = org[c] + (float)ci * vox[c] - q;
            float rel0 = fmaxf(base, lim[c]);
            float g = fminf(fmaxf((rel0 - 0.5f) * 2.0f, -1.0f + 1e-7f), 1.0f - 1e-7f);
            ptQ[c][p] = q; ptCI[c][p] = ci; ptBase[c][p] = base; ptT[c][p] = (g + 1.0f) * 0.5f;
        }
    }
    __syncthreads();

    // trilinear corner weights (reference's channel swap: i->t[2], j->t[1], k->t[0])
    if (tid < 128) {
        int p = tid >> 3, corner = tid & 7;
        int i = corner >> 2, j = (corner >> 1) & 1, k = corner & 1;
        float wx = i ? ptT[2][p] : 1.0f - ptT[2][p];
        float wy = j ? ptT[1][p] : 1.0f - ptT[1][p];
        float wz = k ? ptT[0][p] : 1.0f - ptT[0][p];
        wcorn[p][corner] = wx * wy * wz;
    }

    // gather (coalesced bf16 cvT) + coord features; 2 threads per batch row
    {
        const int r = tid >> 1, h = tid & 1;
        const int p = r >> 3, corner = r & 7;
        const int i0 = corner >> 2, i1 = (corner >> 1) & 1, i2 = corner & 1;
        int io[3] = {i0, i1, i2};

        int cell = (ptCI[0][p] + i0) * 1024 + (ptCI[1][p] + i1) * 32 + ptCI[2][p] + i2;
        const uint4* src = (const uint4*)&cvT[cell * 96];
        uint4* dstX = (uint4*)&Xin[r * SA];
        #pragma unroll
        for (int cc = h * 6; cc < h * 6 + 6; ++cc) dstX[cc] = src[cc];

        float rn[3];
        #pragma unroll
        for (int c = 0; c < 3; ++c) {
            float rel = fmaxf(ptBase[c][p] + (float)io[c] * vox[c], lim[c]);
            rn[c] = (rel - mrel[c][io[c]]) * inv3v[c];
        }
        ushort_t* row = &Xin[r * SA];
        if (h == 0) {
            #pragma unroll
            for (int c = 0; c < 3; ++c) {
                row[96 + c]  = f2bf(qv[c]);
                row[99 + c]  = f2bf(org[c] + (float)(ptCI[c][p] + io[c]) * vox[c]);
                row[102 + c] = f2bf(ptQ[c][p]);
                row[105 + c] = f2bf(rn[c]);
            }
            #pragma unroll
            for (int z = 156; z < SA; ++z) row[z] = 0;
            #pragma unroll
            for (int m = 0; m < 8; ++m) {
                float ang = rn[0] * FREQ[m];
#if FAST_SINCOS
                float fr = __builtin_amdgcn_fractf(ang);
                row[108 + m] = f2bf(__builtin_amdgcn_sinf(fr));
                row[116 + m] = f2bf(__builtin_amdgcn_cosf(fr));
#else
                float s, co; sincospif(2.0f * ang, &s, &co);
                row[108 + m] = f2bf(s); row[116 + m] = f2bf(co);
#endif
            }
        } else {
            #pragma unroll
            for (int c = 1; c < 3; ++c) {
                #pragma unroll
                for (int m = 0; m < 8; ++m) {
                    float ang = rn[c] * FREQ[m];
#if FAST_SINCOS
                    float fr = __builtin_amdgcn_fractf(ang);
                    row[108 + c * 16 + m] = f2bf(__builtin_amdgcn_sinf(fr));
                    row[108 + c * 16 + 8 + m] = f2bf(__builtin_amdgcn_cosf(fr));
#else
                    float s, co; sincospif(2.0f * ang, &s, &co);
                    row[108 + c * 16 + m] = f2bf(s);
                    row[108 + c * 16 + 8 + m] = f2bf(co);
#endif
                }
            }
        }
    }
    __syncthreads();   // LAST block-wide barrier before the post-GEMM one

    const int A32off[2] = {L0A, L0B};
    const int A16off[2][2] = {{A1_00, A1_01}, {A1_10, A1_11}};
    floatx4 acc[6][2];     // C-layout: channel mt*16+quad*4+r of column col0+nt*16+l16
    shrt4 bfr[6][2];       // bf16-packed == B-fragments for 16x16x16

    #pragma unroll
    for (int blk = 0; blk < 2; ++blk) {
        // ---- layer 0: K=160, mfma 16x16x32; B from Xin (wave-private cols), A from L2
        {
            short8 bX[2][5];
            #pragma unroll
            for (int nt = 0; nt < 2; ++nt)
                #pragma unroll
                for (int kc = 0; kc < 5; ++kc)
                    bX[nt][kc] = *(const short8*)&Xin[(col0 + nt * 16 + l16) * SA + kc * 32 + quad8];
            #pragma unroll
            for (int mt = 0; mt < 6; ++mt) {
                short8 aw[5];
                #pragma unroll
                for (int kc = 0; kc < 5; ++kc)
                    aw[kc] = *(const short8*)&wsW[A32off[blk] + ((mt * 5 + kc) << 9) + lane8];
                #pragma unroll
                for (int nt = 0; nt < 2; ++nt) {
                    floatx4 a = {0.f, 0.f, 0.f, 0.f};
                    #pragma unroll
                    for (int kc = 0; kc < 5; ++kc)
                        a = __builtin_amdgcn_mfma_f32_16x16x32_bf16(aw[kc], bX[nt][kc], a, 0, 0, 0);
                    acc[mt][nt] = a;
                }
            }
        }
        {   // epilogue l0: bias + silu -> B-fragments (registers only)
            const int lay = blk * 3;
            #pragma unroll
            for (int mt = 0; mt < 6; ++mt) {
                floatx4 bv = *(const floatx4*)&biasF[((lay * 6 + mt) << 8) + (lane << 2)];
                #pragma unroll
                for (int nt = 0; nt < 2; ++nt) {
                    floatx4 s;
                    #pragma unroll
                    for (int r = 0; r < 4; ++r) {
                        float z = acc[mt][nt][r] + bv[r];
                        s[r] = z * __builtin_amdgcn_rcpf(1.0f + __expf(-z));
                    }
                    bfr[mt][nt] = pk4(s);
                }
            }
        }
        // ---- layers 1,2: K=96, mfma 16x16x16 chained from registers
        #pragma unroll
        for (int l = 1; l < 3; ++l) {
            #pragma unroll
            for (int mt = 0; mt < 6; ++mt) {
                short8 awp[3];
                #pragma unroll
                for (int kp = 0; kp < 3; ++kp)
                    awp[kp] = *(const short8*)&wsW[A16off[blk][l - 1] + ((mt * 3 + kp) << 9) + lane8];
                #pragma unroll
                for (int nt = 0; nt < 2; ++nt) {
                    floatx4 a = {0.f, 0.f, 0.f, 0.f};
                    #pragma unroll
                    for (int kc = 0; kc < 6; ++kc) {
                        shrt4 af = (kc & 1)
                            ? __builtin_shufflevector(awp[kc >> 1], awp[kc >> 1], 4, 5, 6, 7)
                            : __builtin_shufflevector(awp[kc >> 1], awp[kc >> 1], 0, 1, 2, 3);
                        a = MFMA16(af, bfr[kc][nt], a);
                    }
                    acc[mt][nt] = a;
                }
            }
            const int lay = blk * 3 + l;
            if (l == 1) {   // epilogue -> B-fragments
                #pragma unroll
                for (int mt = 0; mt < 6; ++mt) {
                    floatx4 bv = *(const floatx4*)&biasF[((lay * 6 + mt) << 8) + (lane << 2)];
                    #pragma unroll
                    for (int nt = 0; nt < 2; ++nt) {
                        floatx4 s;
                        #pragma unroll
                        for (int r = 0; r < 4; ++r) {
                            float z = acc[mt][nt][r] + bv[r];
                            s[r] = z * __builtin_amdgcn_rcpf(1.0f + __expf(-z));
                        }
                        bfr[mt][nt] = pk4(s);
                    }
                }
            } else {        // epilogue l2: silu + residual (from Xin) + h write-back (wave-private)
                #pragma unroll
                for (int mt = 0; mt < 6; ++mt) {
                    floatx4 bv = *(const floatx4*)&biasF[((lay * 6 + mt) << 8) + (lane << 2)];
                    #pragma unroll
                    for (int nt = 0; nt < 2; ++nt) {
                        int ca = (col0 + nt * 16 + l16) * SA + mt * 16 + quad4;
                        ush4 hu = *(const ush4*)&Xin[ca];      // residual source (X0-h or blk0-h)
                        floatx4 s;
                        #pragma unroll
                        for (int r = 0; r < 4; ++r) {
                            float z = acc[mt][nt][r] + bv[r];
                            s[r] = z * __builtin_amdgcn_rcpf(1.0f + __expf(-z)) + bf2f(hu[r]);
                        }
                        uintx2 w;
                        w[0] = (unsigned)f2bf(s[0]) | ((unsigned)f2bf(s[1]) << 16);
                        w[1] = (unsigned)f2bf(s[2]) | ((unsigned)f2bf(s[3]) << 16);
                        *(uintx2*)&Xin[ca] = w;                // same-wave readers only
                    }
                }
            }
        }
    }

    // blend 8 corners -> Hhat (wave-private: p = tid>>4 lies in this wave's columns)
    {
        int p = tid >> 4, s6 = (tid & 15) * 6;
        float w8[8];
        #pragma unroll
        for (int c = 0; c < 8; ++c) w8[c] = wcorn[p][c];
        #pragma unroll
        for (int cc = 0; cc < 6; ++cc) {
            int col = s6 + cc;
            float sum = 0.f;
            #pragma unroll
            for (int c = 0; c < 8; ++c) sum += w8[c] * bf2f(Xin[(p * 8 + c) * SA + col]);
            Hhat[p * SW + col] = f2bf(sum);
        }
    }
    __syncthreads();   // Hhat is read cross-wave by the post GEMM

    // post GEMM: 16 points x 48(45) out channels
    if (wv < 3) {
        const ushort_t* wb = wsW + PST;
        floatx4 pacc = {0.f, 0.f, 0.f, 0.f};
        #pragma unroll
        for (int kc = 0; kc < 3; ++kc) {
            short8 a = *(const short8*)&Hhat[l16 * SW + kc * 32 + quad8];
            short8 bfrag = *(const short8*)&wb[((wv * 3 + kc) << 9) + lane8];
            pacc = __builtin_amdgcn_mfma_f32_16x16x32_bf16(a, bfrag, pacc, 0, 0, 0);
        }
        int n = 16 * wv + l16;
        if (n < 45) {
            float bv = pb[n];
            float4 v;
            v.x = pacc[0] + bv; v.y = pacc[1] + bv; v.z = pacc[2] + bv; v.w = pacc[3] + bv;
            *(float4*)&out[n * NQ + p0 + quad * 4] = v;
        }
    }
}

extern "C" void kernel_launch(void* const* d_in, const int* in_sizes, int n_in,
                              void* d_out, int out_size, void* d_ws, size_t ws_size,
                              hipStream_t stream) {
    (void)in_sizes; (void)n_in; (void)out_size; (void)ws_size;
    const float* cv  = (const float*)d_in[0];
    const float* ext = (const float*)d_in[1];
    const float* qvx = (const float*)d_in[2];
    const float* qc  = (const float*)d_in[3];
    const float* w00 = (const float*)d_in[4];
    const float* b00 = (const float*)d_in[5];
    const float* w01 = (const float*)d_in[6];
    const float* b01 = (const float*)d_in[7];
    const float* w02 = (const float*)d_in[8];
    const float* b02 = (const float*)d_in[9];
    const float* w10 = (const float*)d_in[10];
    const float* b10 = (const float*)d_in[11];
    const float* w11 = (const float*)d_in[12];
    const float* b11 = (const float*)d_in[13];
    const float* w12 = (const float*)d_in[14];
    const float* b12 = (const float*)d_in[15];
    const float* pw  = (const float*)d_in[16];
    const float* pb  = (const float*)d_in[17];

    unsigned* keys = (unsigned*)d_ws;
    ushort_t* wsW  = (ushort_t*)((char*)d_ws + WSW_OFF);
    float* biasF   = (float*)((char*)d_ws + BIAS_OFF);
    ushort_t* cvT  = (ushort_t*)((char*)d_ws + CVT_OFF);

    decoder_txp<<<256, 256, 0, stream>>>(cv, cvT);
    decoder_prep<<<318, 256, 0, stream>>>(w00, b00, w01, b01, w02, b02,
                                          w10, b10, w11, b11, w12, b12,
                                          pw, wsW, biasF, keys);
    decoder_prepass<<<432, 256, 0, stream>>>(qc, ext, keys);
    decoder_main<<<6912, 256, 0, stream>>>(cvT, ext, qvx, qc,
                                           pb, wsW, biasF, keys, (float*)d_out);
}

// Round 7
// 322.921 us; speedup vs baseline: 3.3830x; 1.1047x over previous
//
#include <hip/hip_runtime.h>
#include <hip/hip_bf16.h>

typedef unsigned short ushort_t;
typedef short short8 __attribute__((ext_vector_type(8)));
typedef short shrt4 __attribute__((ext_vector_type(4)));
typedef unsigned short ush4 __attribute__((ext_vector_type(4)));
typedef unsigned int uintx2 __attribute__((ext_vector_type(2)));
typedef float floatx4 __attribute__((ext_vector_type(4)));

#define SA 168   // Xin row stride in bf16 elems: 336B = 21*16
#define SW 104   // Hhat stride
#define NQ 110592
#define CVOL 32768

// wsW bf16 element offsets
#define L0A   0        // blk0 l0 weights, 16x16x32 A-layout [mt6][kc5][lane][8]
#define L0B   15360    // blk1 l0
#define A1_00 30720    // blk0 l1 weights, 16x16x16 A-layout [mt6][kp3][lane][kl2*4+i]
#define A1_01 39936    // blk0 l2
#define A1_10 49152    // blk1 l1
#define A1_11 58368    // blk1 l2
#define PST   67584    // post weights, 16x16x32 B-layout
#define WTOT  72192
#define BTOT  9216     // bias floats, C-layout [layer6][mt6][lane][r4]

// ws byte offsets
#define WSW_OFF  64
#define BIAS_OFF 147456
#define CVT_OFF  196608

// merged pre-kernel block ranges
#define TXP_NB   256
#define PREP_NB  318
#define PRE_NB   (TXP_NB + PREP_NB + 432)

#if defined(__HIP_DEVICE_COMPILE__)
#define MFMA16(A, B, C) __builtin_amdgcn_mfma_f32_16x16x16bf16_1k(A, B, C, 0, 0, 0)
#else
#define MFMA16(A, B, C) (C)
#endif

#if defined(__HIP_DEVICE_COMPILE__) && __has_builtin(__builtin_amdgcn_sinf) && __has_builtin(__builtin_amdgcn_cosf) && __has_builtin(__builtin_amdgcn_fractf)
#define FAST_SINCOS 1
#else
#define FAST_SINCOS 0
#endif

__device__ __forceinline__ float bf2f(ushort_t u) { return __uint_as_float(((unsigned)u) << 16); }
__device__ __forceinline__ ushort_t f2bf(float f) {         // exact RNE (cold paths)
    unsigned u = __float_as_uint(f);
    unsigned r = (u + 0x7fffu + ((u >> 16) & 1u)) >> 16;
    return (ushort_t)r;
}
// hot-path pack: two f32 -> packed bf16 pair. cvt_pk if HW has it, else
// round-half-up (+0x8000) + v_perm (1.5 ops/elem; differs from RNE only on exact ties).
__device__ __forceinline__ unsigned pkpair(float a, float b) {
#if defined(__HIP_DEVICE_COMPILE__) && __has_builtin(__builtin_amdgcn_cvt_pk_bf16_f32)
    return __builtin_bit_cast(unsigned, __builtin_amdgcn_cvt_pk_bf16_f32(a, b));
#else
    unsigned ua = __float_as_uint(a) + 0x8000u;
    unsigned ub = __float_as_uint(b) + 0x8000u;
    return __builtin_amdgcn_perm(ub, ua, 0x07060302);   // lo16=hi(ua), hi16=hi(ub)
#endif
}
__device__ __forceinline__ shrt4 pk4(floatx4 v) {
    uintx2 u;
    u[0] = pkpair(v[0], v[1]);
    u[1] = pkpair(v[2], v[3]);
    return __builtin_bit_cast(shrt4, u);
}
__device__ __forceinline__ unsigned encodeMin(float x) {
    unsigned u = __float_as_uint(x);
    return (u & 0x80000000u) ? ~u : (u | 0x80000000u);
}
__device__ __forceinline__ float decodeMin(unsigned key) {
    unsigned u = (key & 0x80000000u) ? (key ^ 0x80000000u) : ~key;
    return __uint_as_float(u);
}

__device__ __constant__ float FREQ[8] = {
    1.0f, 1.2228445f, 1.4953488f, 1.8285791f,
    2.2360680f, 2.7343640f, 3.3437015f, 4.0888269f
};

// ---------------- merged pre-kernel: txp | weight/bias swizzle | min-prepass ----------------
// keys must be pre-initialized to 0xFFFFFFFF (hipMemsetAsync in kernel_launch).
__global__ void decoder_pre(const float* __restrict__ cv, ushort_t* __restrict__ cvT,
                            const float* __restrict__ w00, const float* __restrict__ b00,
                            const float* __restrict__ w01, const float* __restrict__ b01,
                            const float* __restrict__ w02, const float* __restrict__ b02,
                            const float* __restrict__ w10, const float* __restrict__ b10,
                            const float* __restrict__ w11, const float* __restrict__ b11,
                            const float* __restrict__ w12, const float* __restrict__ b12,
                            const float* __restrict__ pw, ushort_t* __restrict__ wsW,
                            float* __restrict__ biasF,
                            const float* __restrict__ qc, const float* __restrict__ ext,
                            unsigned* __restrict__ keys) {
    __shared__ ushort_t ld[128 * SW];
    __shared__ unsigned mk[3];
    const int bx = blockIdx.x;
    const int tid = threadIdx.x;

    if (bx < TXP_NB) {            // ---- transpose cv [96][32768] fp32 -> cvT [32768][96] bf16
        int base = bx * 128;
        int cl = tid & 127, h = tid >> 7;
        #pragma unroll 4
        for (int ch = h * 48; ch < h * 48 + 48; ++ch)
            ld[cl * SW + ch] = f2bf(cv[ch * CVOL + base + cl]);
        __syncthreads();
        #pragma unroll
        for (int it = 0; it < 6; ++it) {
            int idx = it * 256 + tid;
            int r = idx / 12, c = idx - r * 12;
            *(uint4*)&cvT[(base + r) * 96 + c * 8] = *(const uint4*)&ld[r * SW + c * 8];
        }
        return;
    }
    if (bx < TXP_NB + PREP_NB) {  // ---- weight swizzle + bias C-layout
        int idx = (bx - TXP_NB) * 256 + tid;
        if (idx >= WTOT + BTOT) return;
        if (idx >= WTOT) {
            int t = idx - WTOT;
            int layer = t / 1536, rem = t - layer * 1536;
            int mt = rem >> 8, l2i = rem & 255;
            int lane = l2i >> 2, r = l2i & 3;
            int m = mt * 16 + (lane >> 4) * 4 + r;
            const float* B = layer == 0 ? b00 : layer == 1 ? b01 : layer == 2 ? b02
                           : layer == 3 ? b10 : layer == 4 ? b11 : b12;
            biasF[t] = B[m];
            return;
        }
        ushort_t v = 0;
        if (idx < A1_00) {            // layer-0 weights: 16x16x32 A-layout
            const float* W = (idx < L0B) ? w00 : w10;
            int li = idx - ((idx < L0B) ? L0A : L0B);
            int j = li & 7, lane = (li >> 3) & 63, chunk = li >> 9;
            int kc = chunk % 5, mt = chunk / 5;
            int k = kc * 32 + (lane >> 4) * 8 + j;
            int m = mt * 16 + (lane & 15);
            if (k < 156) v = f2bf(W[k * 96 + m]);
        } else if (idx < PST) {       // layer-1/2 weights: 16x16x16 A-layout
            const float* W = idx < A1_01 ? w01 : idx < A1_10 ? w02 : idx < A1_11 ? w11 : w12;
            int off = idx < A1_01 ? A1_00 : idx < A1_10 ? A1_01 : idx < A1_11 ? A1_10 : A1_11;
            int li = idx - off;
            int i = li & 3, kl = (li >> 2) & 1, lane = (li >> 3) & 63, chunk = li >> 9;
            int kp = chunk % 3, mt = chunk / 3;
            int k = (kp * 2 + kl) * 16 + (lane >> 4) * 4 + i;
            int m = mt * 16 + (lane & 15);
            v = f2bf(W[k * 96 + m]);
        } else {                      // post weights: 16x16x32 B-layout
            int li = idx - PST;
            int j = li & 7, lane = (li >> 3) & 63, chunk = li >> 9;
            int kc = chunk % 3, t = chunk / 3;
            int k = kc * 32 + (lane >> 4) * 8 + j;
            int n = t * 16 + (lane & 15);
            if (n < 45) v = f2bf(pw[k * 45 + n]);
        }
        wsW[idx] = v;
        return;
    }
    // ---- prepass: global min of base_c = org + ci*vox - q
    {
        int lane = tid & 63;
        if (tid < 3) mk[tid] = 0xFFFFFFFFu;
        __syncthreads();
        int p = (bx - TXP_NB - PREP_NB) * 256 + tid;
        #pragma unroll
        for (int c = 0; c < 3; ++c) {
            float org = ext[c * CVOL];
            float vox = fabsf(ext[c * CVOL + 1057] - org);
            float q = qc[c * NQ + p];
            float nf = rintf((q - org) / vox);
            int ci = (int)nf; ci = ci < 0 ? 0 : (ci > 30 ? 30 : ci);
            float base = org + (float)ci * vox - q;
            for (int off = 32; off > 0; off >>= 1) base = fminf(base, __shfl_xor(base, off));
            if (lane == 0) atomicMin(&mk[c], encodeMin(base));
        }
        __syncthreads();
        if (tid < 3) atomicMin(&keys[tid], mk[tid]);
    }
}

// ---------------- main fused kernel ----------------
__global__ __launch_bounds__(256, 3) void decoder_main(
    const ushort_t* __restrict__ cvT, const float* __restrict__ ext,
    const float* __restrict__ qvx, const float* __restrict__ qc,
    const float* __restrict__ pb, const ushort_t* __restrict__ wsW,
    const float* __restrict__ biasF,
    const unsigned* __restrict__ minKeys, float* __restrict__ out)
{
    __shared__ ushort_t Xin[128 * SA];     // rows = batch (point,corner), cols = [h(96)|feats(60)|pad]
    __shared__ ushort_t Hhat[16 * SW];
    __shared__ float ptQ[3][16], ptBase[3][16], ptT[3][16];
    __shared__ int ptCI[3][16];
    __shared__ float wcorn[16][8];

    const int tid = threadIdx.x;
    const int lane = tid & 63;
    const int wv = tid >> 6;
    const int quad = lane >> 4;
    const int l16 = lane & 15;
    const int lane8 = lane << 3, quad8 = quad * 8, quad4 = quad * 4;
    const int p0 = blockIdx.x * 16;
    const int col0 = wv * 32;              // wave-private batch columns [col0, col0+32)

    // broadcast scalars
    float vox[3], org[3], lim[3], inv3v[3], qv[3], mrel[3][2];
    #pragma unroll
    for (int c = 0; c < 3; ++c) {
        org[c] = ext[c * CVOL];
        vox[c] = fabsf(ext[c * CVOL + 1057] - org[c]);
        lim[c] = -0.5f * vox[c] + 1e-7f;
        inv3v[c] = 1.0f / (1.5f * vox[c]);
        qv[c] = qvx[c];
        float mb = decodeMin(minKeys[c]);
        mrel[c][0] = fmaxf(mb, lim[c]);
        mrel[c][1] = fmaxf(mb + vox[c], lim[c]);
    }

    // per-point setup
    if (tid < 64) {
        int p = tid >> 2, c = tid & 3;
        if (c < 3) {
            float q = qc[c * NQ + p0 + p];
            float nf = rintf((q - org[c]) / vox[c]);   // RNE == jnp.round
            int ci = (int)nf; ci = ci < 0 ? 0 : (ci > 30 ? 30 : ci);
            float base = org[c] + (float)ci * vox[c] - q;
            float rel0 = fmaxf(base, lim[c]);
            float g = fminf(fmaxf((rel0 - 0.5f) * 2.0f, -1.0f + 1e-7f), 1.0f - 1e-7f);
            ptQ[c][p] = q; ptCI[c][p] = ci; ptBase[c][p] = base; ptT[c][p] = (g + 1.0f) * 0.5f;
        }
    }
    __syncthreads();

    // trilinear corner weights (reference's channel swap: i->t[2], j->t[1], k->t[0])
    if (tid < 128) {
        int p = tid >> 3, corner = tid & 7;
        int i = corner >> 2, j = (corner >> 1) & 1, k = corner & 1;
        float wx = i ? ptT[2][p] : 1.0f - ptT[2][p];
        float wy = j ? ptT[1][p] : 1.0f - ptT[1][p];
        float wz = k ? ptT[0][p] : 1.0f - ptT[0][p];
        wcorn[p][corner] = wx * wy * wz;
    }

    // gather (coalesced bf16 cvT) + coord features; 2 threads per batch row
    {
        const int r = tid >> 1, h = tid & 1;
        const int p = r >> 3, corner = r & 7;
        const int i0 = corner >> 2, i1 = (corner >> 1) & 1, i2 = corner & 1;
        int io[3] = {i0, i1, i2};

        int cell = (ptCI[0][p] + i0) * 1024 + (ptCI[1][p] + i1) * 32 + ptCI[2][p] + i2;
        const uint4* src = (const uint4*)&cvT[cell * 96];
        uint4* dstX = (uint4*)&Xin[r * SA];
        #pragma unroll
        for (int cc = h * 6; cc < h * 6 + 6; ++cc) dstX[cc] = src[cc];

        float rn[3];
        #pragma unroll
        for (int c = 0; c < 3; ++c) {
            float rel = fmaxf(ptBase[c][p] + (float)io[c] * vox[c], lim[c]);
            rn[c] = (rel - mrel[c][io[c]]) * inv3v[c];
        }
        ushort_t* row = &Xin[r * SA];
        if (h == 0) {
            #pragma unroll
            for (int c = 0; c < 3; ++c) {
                row[96 + c]  = f2bf(qv[c]);
                row[99 + c]  = f2bf(org[c] + (float)(ptCI[c][p] + io[c]) * vox[c]);
                row[102 + c] = f2bf(ptQ[c][p]);
                row[105 + c] = f2bf(rn[c]);
            }
            #pragma unroll
            for (int z = 156; z < SA; ++z) row[z] = 0;
            #pragma unroll
            for (int m = 0; m < 8; ++m) {
                float ang = rn[0] * FREQ[m];
#if FAST_SINCOS
                float fr = __builtin_amdgcn_fractf(ang);
                row[108 + m] = f2bf(__builtin_amdgcn_sinf(fr));
                row[116 + m] = f2bf(__builtin_amdgcn_cosf(fr));
#else
                float s, co; sincospif(2.0f * ang, &s, &co);
                row[108 + m] = f2bf(s); row[116 + m] = f2bf(co);
#endif
            }
        } else {
            #pragma unroll
            for (int c = 1; c < 3; ++c) {
                #pragma unroll
                for (int m = 0; m < 8; ++m) {
                    float ang = rn[c] * FREQ[m];
#if FAST_SINCOS
                    float fr = __builtin_amdgcn_fractf(ang);
                    row[108 + c * 16 + m] = f2bf(__builtin_amdgcn_sinf(fr));
                    row[108 + c * 16 + 8 + m] = f2bf(__builtin_amdgcn_cosf(fr));
#else
                    float s, co; sincospif(2.0f * ang, &s, &co);
                    row[108 + c * 16 + m] = f2bf(s);
                    row[108 + c * 16 + 8 + m] = f2bf(co);
#endif
                }
            }
        }
    }
    __syncthreads();

    const int A32off[2] = {L0A, L0B};
    const int A16off[2][2] = {{A1_00, A1_01}, {A1_10, A1_11}};
    floatx4 acc[6][2];     // C-layout: channel mt*16+quad*4+r of column col0+nt*16+l16
    shrt4 bfr[6][2];       // bf16-packed == B-fragments for 16x16x16

    #pragma unroll
    for (int blk = 0; blk < 2; ++blk) {
        // ---- layer 0: K=160, mfma 16x16x32; bias rides in as the C operand
        {
            short8 bX[2][5];
            #pragma unroll
            for (int nt = 0; nt < 2; ++nt)
                #pragma unroll
                for (int kc = 0; kc < 5; ++kc)
                    bX[nt][kc] = *(const short8*)&Xin[(col0 + nt * 16 + l16) * SA + kc * 32 + quad8];
            const int lay = blk * 3;
            #pragma unroll
            for (int mt = 0; mt < 6; ++mt) {
                short8 aw[5];
                #pragma unroll
                for (int kc = 0; kc < 5; ++kc)
                    aw[kc] = *(const short8*)&wsW[A32off[blk] + ((mt * 5 + kc) << 9) + lane8];
                floatx4 bv = *(const floatx4*)&biasF[((lay * 6 + mt) << 8) + (lane << 2)];
                #pragma unroll
                for (int nt = 0; nt < 2; ++nt) {
                    floatx4 a = __builtin_amdgcn_mfma_f32_16x16x32_bf16(aw[0], bX[nt][0], bv, 0, 0, 0);
                    #pragma unroll
                    for (int kc = 1; kc < 5; ++kc)
                        a = __builtin_amdgcn_mfma_f32_16x16x32_bf16(aw[kc], bX[nt][kc], a, 0, 0, 0);
                    acc[mt][nt] = a;
                }
            }
        }
        {   // epilogue l0: silu -> B-fragments (bias already in acc)
            #pragma unroll
            for (int mt = 0; mt < 6; ++mt)
                #pragma unroll
                for (int nt = 0; nt < 2; ++nt) {
                    floatx4 s;
                    #pragma unroll
                    for (int r = 0; r < 4; ++r) {
                        float z = acc[mt][nt][r];
                        s[r] = z * __builtin_amdgcn_rcpf(1.0f + __expf(-z));
                    }
                    bfr[mt][nt] = pk4(s);
                }
        }
        // ---- layers 1,2: K=96, mfma 16x16x16 chained from registers
        #pragma unroll
        for (int l = 1; l < 3; ++l) {
            const int lay = blk * 3 + l;
            #pragma unroll
            for (int mt = 0; mt < 6; ++mt) {
                short8 awp[3];
                #pragma unroll
                for (int kp = 0; kp < 3; ++kp)
                    awp[kp] = *(const short8*)&wsW[A16off[blk][l - 1] + ((mt * 3 + kp) << 9) + lane8];
                floatx4 bv = *(const floatx4*)&biasF[((lay * 6 + mt) << 8) + (lane << 2)];
                #pragma unroll
                for (int nt = 0; nt < 2; ++nt) {
                    shrt4 a0 = __builtin_shufflevector(awp[0], awp[0], 0, 1, 2, 3);
                    floatx4 a = MFMA16(a0, bfr[0][nt], bv);
                    #pragma unroll
                    for (int kc = 1; kc < 6; ++kc) {
                        shrt4 af = (kc & 1)
                            ? __builtin_shufflevector(awp[kc >> 1], awp[kc >> 1], 4, 5, 6, 7)
                            : __builtin_shufflevector(awp[kc >> 1], awp[kc >> 1], 0, 1, 2, 3);
                        a = MFMA16(af, bfr[kc][nt], a);
                    }
                    acc[mt][nt] = a;
                }
            }
            if (l == 1) {   // epilogue -> B-fragments
                #pragma unroll
                for (int mt = 0; mt < 6; ++mt)
                    #pragma unroll
                    for (int nt = 0; nt < 2; ++nt) {
                        floatx4 s;
                        #pragma unroll
                        for (int r = 0; r < 4; ++r) {
                            float z = acc[mt][nt][r];
                            s[r] = z * __builtin_amdgcn_rcpf(1.0f + __expf(-z));
                        }
                        bfr[mt][nt] = pk4(s);
                    }
            } else {        // epilogue l2: silu + residual + h write-back (wave-private Xin)
                #pragma unroll
                for (int mt = 0; mt < 6; ++mt)
                    #pragma unroll
                    for (int nt = 0; nt < 2; ++nt) {
                        int ca = (col0 + nt * 16 + l16) * SA + mt * 16 + quad4;
                        ush4 hu = *(const ush4*)&Xin[ca];      // residual source
                        floatx4 s;
                        #pragma unroll
                        for (int r = 0; r < 4; ++r) {
                            float z = acc[mt][nt][r];
                            s[r] = z * __builtin_amdgcn_rcpf(1.0f + __expf(-z)) + bf2f(hu[r]);
                        }
                        uintx2 w;
                        w[0] = pkpair(s[0], s[1]);
                        w[1] = pkpair(s[2], s[3]);
                        *(uintx2*)&Xin[ca] = w;                // same-wave readers only
                    }
            }
        }
    }

    // blend 8 corners -> Hhat (wave-private), b32 reads + hi/lo unpack
    {
        int p = tid >> 4, s6 = (tid & 15) * 6;
        float w8[8];
        #pragma unroll
        for (int c = 0; c < 8; ++c) w8[c] = wcorn[p][c];
        float sum[6] = {0.f, 0.f, 0.f, 0.f, 0.f, 0.f};
        #pragma unroll
        for (int c = 0; c < 8; ++c) {
            const unsigned* rp = (const unsigned*)&Xin[(p * 8 + c) * SA + s6];
            float w = w8[c];
            #pragma unroll
            for (int d = 0; d < 3; ++d) {
                unsigned u = rp[d];
                sum[d * 2]     += w * __uint_as_float(u << 16);
                sum[d * 2 + 1] += w * __uint_as_float(u & 0xFFFF0000u);
            }
        }
        unsigned* hp = (unsigned*)&Hhat[p * SW + s6];
        #pragma unroll
        for (int d = 0; d < 3; ++d) hp[d] = pkpair(sum[d * 2], sum[d * 2 + 1]);
    }
    __syncthreads();   // Hhat is read cross-wave by the post GEMM

    // post GEMM: 16 points x 48(45) out channels
    if (wv < 3) {
        const ushort_t* wb = wsW + PST;
        floatx4 pacc = {0.f, 0.f, 0.f, 0.f};
        #pragma unroll
        for (int kc = 0; kc < 3; ++kc) {
            short8 a = *(const short8*)&Hhat[l16 * SW + kc * 32 + quad8];
            short8 bfrag = *(const short8*)&wb[((wv * 3 + kc) << 9) + lane8];
            pacc = __builtin_amdgcn_mfma_f32_16x16x32_bf16(a, bfrag, pacc, 0, 0, 0);
        }
        int n = 16 * wv + l16;
        if (n < 45) {
            float bv = pb[n];
            float4 v;
            v.x = pacc[0] + bv; v.y = pacc[1] + bv; v.z = pacc[2] + bv; v.w = pacc[3] + bv;
            *(float4*)&out[n * NQ + p0 + quad * 4] = v;
        }
    }
}

extern "C" void kernel_launch(void* const* d_in, const int* in_sizes, int n_in,
                              void* d_out, int out_size, void* d_ws, size_t ws_size,
                              hipStream_t stream) {
    (void)in_sizes; (void)n_in; (void)out_size; (void)ws_size;
    const float* cv  = (const float*)d_in[0];
    const float* ext = (const float*)d_in[1];
    const float* qvx = (const float*)d_in[2];
    const float* qc  = (const float*)d_in[3];
    const float* w00 = (const float*)d_in[4];
    const float* b00 = (const float*)d_in[5];
    const float* w01 = (const float*)d_in[6];
    const float* b01 = (const float*)d_in[7];
    const float* w02 = (const float*)d_in[8];
    const float* b02 = (const float*)d_in[9];
    const float* w10 = (const float*)d_in[10];
    const float* b10 = (const float*)d_in[11];
    const float* w11 = (const float*)d_in[12];
    const float* b11 = (const float*)d_in[13];
    const float* w12 = (const float*)d_in[14];
    const float* b12 = (const float*)d_in[15];
    const float* pw  = (const float*)d_in[16];
    const float* pb  = (const float*)d_in[17];

    unsigned* keys = (unsigned*)d_ws;
    ushort_t* wsW  = (ushort_t*)((char*)d_ws + WSW_OFF);
    float* biasF   = (float*)((char*)d_ws + BIAS_OFF);
    ushort_t* cvT  = (ushort_t*)((char*)d_ws + CVT_OFF);

    hipMemsetAsync(keys, 0xFF, 12, stream);   // atomicMin identity (graph-safe)
    decoder_pre<<<PRE_NB, 256, 0, stream>>>(cv, cvT,
                                            w00, b00, w01, b01, w02, b02,
                                            w10, b10, w11, b11, w12, b12,
                                            pw, wsW, biasF, qc, ext, keys);
    decoder_main<<<6912, 256, 0, stream>>>(cvT, ext, qvx, qc,
                                           pb, wsW, biasF, keys, (float*)d_out);
}